// Round 4
// baseline (576.144 us; speedup 1.0000x reference)
//
#include <hip/hip_runtime.h>
#include <math.h>

#define KCOMP 4
#define NN 2048
#define EE 4096
#define DD 128
#define MAXNE 96
#define MAXSE 500
#define BETA_C 0.6f
#define EPS_G 0.01f
#define LAM_S 0.05f
#define TC0_C 0.3f
#define TCMAX_C 0.7f
#define COS_EPS_C 1e-8f

// ---- workspace layout (bytes) ----
static const size_t OFF_XHAT   = 0;          // N*D f32 = 1 MB
static const size_t OFF_XNORM  = 1048576;    // N f32 = 8 KB
static const size_t OFF_SCAL   = 1056768;    // 256 B
static const size_t OFF_NCNT   = 1057024;    // K*N i32 = 32 KB (contiguous with SCAL for one memset)
static const size_t OFF_EMASK  = 1089792;    // K*E*32 u64 = 4 MB (fully overwritten, no zeroing)
static const size_t OFF_NELIST = 5284096;    // K*N*96 u16 = 1.5 MB
static const size_t OFF_EGS    = 6856960;    // K*E f32 = 64 KB (gates[k]*eg_eff[e])
static const size_t OFF_Z      = 6922496;    // K*N f32 = 32 KB

// ---------- xhat / xnorm : wave per node ----------
__global__ void k_xhat(const float* __restrict__ X, float* __restrict__ xhat,
                       float* __restrict__ xnorm) {
  int wid  = (blockIdx.x * blockDim.x + threadIdx.x) >> 6;
  int lane = threadIdx.x & 63;
  if (wid >= NN) return;
  float2 v = ((const float2*)X)[(size_t)wid * 64 + lane];
  float ss = v.x * v.x + v.y * v.y;
  for (int o = 32; o > 0; o >>= 1) ss += __shfl_xor(ss, o, 64);
  float nrm = sqrtf(ss);
  float den = fmaxf(nrm, COS_EPS_C);
  if (lane == 0) xnorm[wid] = nrm;
  float2 o2; o2.x = v.x / den; o2.y = v.y / den;
  ((float2*)xhat)[(size_t)wid * 64 + lane] = o2;
}

// ---------- single pass over H: register-accumulated emask words (no atomicOr)
// + node->edge lists. chunk ch owns rows [ch*64, ch*64+64) == emask word ch. ----------
__global__ void k_scan(const float4* __restrict__ H4, unsigned long long* __restrict__ emask,
                       int* __restrict__ ncnt, unsigned short* __restrict__ nelist) {
  int gid = blockIdx.x * blockDim.x + threadIdx.x;   // [k][ch][e4]
  int e4 = gid & (EE / 4 - 1);
  int t  = gid >> 10;
  int ch = t & 31;
  int k  = t >> 5;
  int n0 = ch * 64;
  const float4* p = H4 + ((size_t)k * NN + n0) * (EE / 4) + e4;
  unsigned long long w0 = 0, w1 = 0, w2 = 0, w3 = 0;
  int ebase = e4 * 4;
  for (int r = 0; r < 64; ++r) {
    float4 v = p[(size_t)r * (EE / 4)];
    bool h0 = v.x > 0.f, h1 = v.y > 0.f, h2 = v.z > 0.f, h3 = v.w > 0.f;
    unsigned long long bit = 1ULL << r;
    if (h0) w0 |= bit;
    if (h1) w1 |= bit;
    if (h2) w2 |= bit;
    if (h3) w3 |= bit;
    if (h0 | h1 | h2 | h3) {
      int n = n0 + r;
      int cnt = (int)h0 + (int)h1 + (int)h2 + (int)h3;
      int slot = atomicAdd(&ncnt[k * NN + n], cnt);
      size_t nb = ((size_t)(k * NN + n)) * MAXNE;
      if (h0) { if (slot < MAXNE) nelist[nb + slot] = (unsigned short)(ebase + 0); slot++; }
      if (h1) { if (slot < MAXNE) nelist[nb + slot] = (unsigned short)(ebase + 1); slot++; }
      if (h2) { if (slot < MAXNE) nelist[nb + slot] = (unsigned short)(ebase + 2); slot++; }
      if (h3) { if (slot < MAXNE) nelist[nb + slot] = (unsigned short)(ebase + 3); slot++; }
    }
  }
  size_t base = ((size_t)(k * EE) + ebase) * 32 + ch;
  emask[base]      = w0;
  emask[base + 32] = w1;
  emask[base + 64] = w2;
  emask[base + 96] = w3;
}

// ---------- fused MLP chain, 16-node tiles ----------
__global__ void k_mlp(const float* __restrict__ X,
                      const float* __restrict__ w1, const float* __restrict__ b1,
                      const float* __restrict__ w2, const float* __restrict__ b2,
                      const float* __restrict__ aw1, const float* __restrict__ ab1,
                      const float* __restrict__ aw2, const float* __restrict__ ab2,
                      float* __restrict__ scal) {
  __shared__ float Xs[16 * 128];
  __shared__ float H1s[16 * 128];
  __shared__ float XKs[16 * 128];
  __shared__ float A1s[16 * 64];
  __shared__ float red[16];
  int t = threadIdx.x;
  int k = blockIdx.y;
  int n0 = blockIdx.x * 16;
  for (int i = t; i < 16 * 128; i += 256) Xs[i] = X[(size_t)n0 * 128 + i];
  __syncthreads();

  int h = t & 127, g = t >> 7;
  const float* W1 = w1 + (size_t)k * 128 * 128;
  float acc[8];
  float bb = b1[k * 128 + h];
#pragma unroll
  for (int i = 0; i < 8; i++) acc[i] = bb;
  for (int d = 0; d < 128; ++d) {
    float w = W1[d * 128 + h];
#pragma unroll
    for (int i = 0; i < 8; i++) acc[i] = fmaf(Xs[(g * 8 + i) * 128 + d], w, acc[i]);
  }
#pragma unroll
  for (int i = 0; i < 8; i++) H1s[(g * 8 + i) * 128 + h] = fmaxf(acc[i], 0.f);
  __syncthreads();

  const float* W2 = w2 + (size_t)k * 128 * 128;
  bb = b2[k * 128 + h];
#pragma unroll
  for (int i = 0; i < 8; i++) acc[i] = bb;
  for (int d = 0; d < 128; ++d) {
    float w = W2[d * 128 + h];
#pragma unroll
    for (int i = 0; i < 8; i++) acc[i] = fmaf(H1s[(g * 8 + i) * 128 + d], w, acc[i]);
  }
  float fpart = 0.f;
#pragma unroll
  for (int i = 0; i < 8; i++) { XKs[(g * 8 + i) * 128 + h] = acc[i]; fpart = fmaf(acc[i], acc[i], fpart); }
  __syncthreads();

  int h2 = t & 63, g4 = t >> 6;
  const float* AW1 = aw1 + (size_t)k * 128 * 64;
  float a4[4];
  float ab = ab1[k * 64 + h2];
#pragma unroll
  for (int i = 0; i < 4; i++) a4[i] = ab;
  for (int d = 0; d < 128; ++d) {
    float w = AW1[d * 64 + h2];
#pragma unroll
    for (int i = 0; i < 4; i++) a4[i] = fmaf(XKs[(g4 * 4 + i) * 128 + d], w, a4[i]);
  }
#pragma unroll
  for (int i = 0; i < 4; i++) A1s[(g4 * 4 + i) * 64 + h2] = fmaxf(a4[i], 0.f);
  __syncthreads();

  float attsum = 0.f;
  if (t < 16) {
    const float* AW2 = aw2 + (size_t)k * 64;
    float a = ab2[k];
    for (int d = 0; d < 64; ++d) a = fmaf(A1s[t * 64 + d], AW2[d], a);
    attsum = 1.f / (1.f + expf(-a));
  }
  for (int o = 32; o > 0; o >>= 1) {
    fpart  += __shfl_xor(fpart, o, 64);
    attsum += __shfl_xor(attsum, o, 64);
  }
  int wv = t >> 6, ln = t & 63;
  if (ln == 0) { red[wv] = fpart; red[8 + wv] = attsum; }
  __syncthreads();
  if (t == 0) {
    float fs = red[0] + red[1] + red[2] + red[3];
    float as = red[8] + red[9] + red[10] + red[11];
    atomicAdd(&scal[0 + k], fs);
    atomicAdd(&scal[4 + k], as);
  }
}

// ---------- component gates (frobenius fused in), one block ----------
__global__ void k_gates(const float* __restrict__ W, float* __restrict__ scal,
                        const int* __restrict__ epoch, float* __restrict__ out_gates) {
  __shared__ float fro[4];
  int t = threadIdx.x, k = t >> 6, lane = t & 63;
  const float* p = W + (size_t)k * 16384;
  float s = 0.f;
  for (int i = lane; i < 16384; i += 64) { float v = p[i]; s = fmaf(v, v, s); }
  for (int o = 32; o > 0; o >>= 1) s += __shfl_xor(s, o, 64);
  if (lane == 0) fro[k] = s;
  __syncthreads();
  if (t != 0) return;
  float imp[KCOMP];
  for (int kk = 0; kk < KCOMP; kk++) {
    float featn = sqrtf(scal[0 + kk]);
    float satt  = scal[4 + kk] / (float)NN;
    float frob  = sqrtf(fro[kk]);
    imp[kk] = BETA_C * frob * featn + (1.f - BETA_C) * satt;
  }
  float m = imp[0];
  for (int kk = 1; kk < KCOMP; kk++) m = fmaxf(m, imp[kk]);
  float ex[KCOMP], ssum = 0.f;
  for (int kk = 0; kk < KCOMP; kk++) { ex[kk] = expf(imp[kk] - m); ssum += ex[kk]; }
  float tc = TC0_C + (1.f - expf(-LAM_S * (float)epoch[0])) * (TCMAX_C - TC0_C);
  float gates[KCOMP];
  for (int kk = 0; kk < KCOMP; kk++) {
    float pi = ex[kk] / ssum;
    gates[kk] = fminf(fmaxf((pi - tc) / EPS_G + 0.5f, 0.f), 1.f);
  }
  int am = 0; float bv = gates[0];
  for (int kk = 1; kk < KCOMP; kk++) if (gates[kk] > bv) { bv = gates[kk]; am = kk; }
  gates[am] = fmaxf(gates[am], 1.f);
  for (int kk = 0; kk < KCOMP; kk++) { scal[12 + kk] = gates[kk]; out_gates[kk] = gates[kk]; }
  scal[16] = tc;
}

// ---------- fused edge-importance + softmax + gating, one block per k ----------
__device__ __forceinline__ float blockReduceSum16(float v, float* red, int t) {
  for (int o = 32; o > 0; o >>= 1) v += __shfl_xor(v, o, 64);
  __syncthreads();
  if ((t & 63) == 0) red[t >> 6] = v;
  __syncthreads();
  float s = red[0];
#pragma unroll
  for (int i = 1; i < 16; i++) s += red[i];
  return s;
}

__global__ void k_edgegate(const unsigned long long* __restrict__ emask,
                           const float* __restrict__ xhat, const float* __restrict__ scal,
                           float* __restrict__ egscaled, float* __restrict__ out_eg) {
  __shared__ float impL[512];
  __shared__ float red[16];
  __shared__ int redi[16];
  int k = blockIdx.x;
  int t = threadIdx.x;
  int wv = t >> 6, lane = t & 63;
  // --- cosine importance for first 500 edges; wave wv owns e = wv*32 .. +31 ---
  for (int ei = 0; ei < 32; ++ei) {
    int e = wv * 32 + ei;
    if (e >= MAXSE) break;                       // wave-uniform
    unsigned long long w = 0;
    if (lane < 32) w = emask[((size_t)(k * EE + e)) * 32 + lane];
    int pc = __popcll(w);
    for (int o = 32; o > 0; o >>= 1) pc += __shfl_xor(pc, o, 64);
    float impv = 0.1f;
    if (pc >= 2) {     // H binary -> A_ij = 1; i,j = two lowest set bits
      unsigned int l1 = w ? (unsigned)(__builtin_ctzll(w) + (lane << 6)) : 0xffffffffu;
      unsigned long long wr = w & (w - 1);
      unsigned int l2 = wr ? (unsigned)(__builtin_ctzll(wr) + (lane << 6)) : 0xffffffffu;
      unsigned int g1 = l1;
      for (int o = 32; o > 0; o >>= 1) {
        unsigned int x = (unsigned)__shfl_xor((int)g1, o, 64);
        g1 = g1 < x ? g1 : x;
      }
      unsigned int cand = (l1 == g1) ? l2 : l1;
      unsigned int g2 = cand;
      for (int o = 32; o > 0; o >>= 1) {
        unsigned int x = (unsigned)__shfl_xor((int)g2, o, 64);
        g2 = g2 < x ? g2 : x;
      }
      float2 xi = ((const float2*)xhat)[(size_t)g1 * 64 + lane];
      float2 xj = ((const float2*)xhat)[(size_t)g2 * 64 + lane];
      float d = xi.x * xj.x + xi.y * xj.y;
      for (int o = 32; o > 0; o >>= 1) d += __shfl_xor(d, o, 64);
      impv = d;
    }
    if (lane == 0) impL[e] = impv;
  }
  __syncthreads();
  // --- softmax over all E with only first 500 scored ---
  float imp[4];
#pragma unroll
  for (int j = 0; j < 4; j++) {
    int e = t + j * 1024;
    imp[j] = (e < MAXSE) ? impL[e] : 0.f;
  }
  float m = fmaxf(fmaxf(imp[0], imp[1]), fmaxf(imp[2], imp[3]));
  for (int o = 32; o > 0; o >>= 1) m = fmaxf(m, __shfl_xor(m, o, 64));
  __syncthreads();
  if ((t & 63) == 0) red[t >> 6] = m;
  __syncthreads();
  m = red[0];
#pragma unroll
  for (int i = 1; i < 16; i++) m = fmaxf(m, red[i]);
  float p[4], psum = 0.f;
#pragma unroll
  for (int j = 0; j < 4; j++) { p[j] = expf(imp[j] - m); psum += p[j]; }
  float S = blockReduceSum16(psum, red, t);
  float pi[4], tot = 0.f;
#pragma unroll
  for (int j = 0; j < 4; j++) { pi[j] = p[j] / S; tot += pi[j]; }
  float T = blockReduceSum16(tot, red, t);
  float mean = T / (float)EE;
  float devs = 0.f;
#pragma unroll
  for (int j = 0; j < 4; j++) { float d = pi[j] - mean; devs = fmaf(d, d, devs); }
  float V = blockReduceSum16(devs, red, t);
  float stdv = sqrtf(V / (float)(EE - 1));
  float theta = fminf(scal[16], mean + stdv);
  float eg[4], egsum = 0.f;
#pragma unroll
  for (int j = 0; j < 4; j++) {
    eg[j] = fminf(fmaxf((pi[j] - theta) / EPS_G + 0.5f, 0.f), 1.f);
    egsum += eg[j];
  }
  float EGS = blockReduceSum16(egsum, red, t);
  float bv = -1e30f; int bi = 0x7fffffff;
#pragma unroll
  for (int j = 0; j < 4; j++) if (pi[j] > bv) { bv = pi[j]; bi = t + j * 1024; }
  for (int o = 32; o > 0; o >>= 1) {
    float ov = __shfl_xor(bv, o, 64); int oi = __shfl_xor(bi, o, 64);
    if (ov > bv || (ov == bv && oi < bi)) { bv = ov; bi = oi; }
  }
  __syncthreads();
  if ((t & 63) == 0) { red[t >> 6] = bv; redi[t >> 6] = bi; }
  __syncthreads();
  float abv = red[0]; int abi = redi[0];
#pragma unroll
  for (int i = 1; i < 16; i++) {
    float ov = red[i]; int oi = redi[i];
    if (ov > abv || (ov == abv && oi < abi)) { abv = ov; abi = oi; }
  }
  float g = scal[12 + k];
#pragma unroll
  for (int j = 0; j < 4; j++) {
    int e = t + j * 1024;
    float egv = eg[j];
    if (EGS < 1.f && e == abi) egv = 1.f;
    out_eg[(size_t)k * EE + e] = egv;
    float eff = (g > 0.5f) ? egv : 1.f;
    egscaled[k * EE + e] = g * eff;
  }
}

// ---------- Hp: compose each output row in LDS, stream out dense (no d_out pre-zero) ----------
__global__ void k_hp(const int* __restrict__ ncnt, const unsigned short* __restrict__ nelist,
                     const float* __restrict__ egs, float* __restrict__ out) {
  __shared__ float row[EE];
  int k = blockIdx.y, n = blockIdx.x, t = threadIdx.x;
  float4* row4 = (float4*)row;
  float4 z4 = {0.f, 0.f, 0.f, 0.f};
#pragma unroll
  for (int i = 0; i < 4; i++) row4[t + i * 256] = z4;
  __syncthreads();
  int ec = ncnt[k * NN + n]; if (ec > MAXNE) ec = MAXNE;
  if (t < ec) {
    int e = nelist[((size_t)(k * NN + n)) * MAXNE + t];
    row[e] = egs[k * EE + e];
  }
  __syncthreads();
  float4* o4 = (float4*)(out + ((size_t)(k * NN + n)) * EE);
#pragma unroll
  for (int i = 0; i < 4; i++) o4[t + i * 256] = row4[t + i * 256];
}

// ---------- fused adjacency-build + row scan: block per (n,k), no global atomics ----------
__global__ void k_rowscan(const unsigned long long* __restrict__ emask,
                          const int* __restrict__ ncnt, const unsigned short* __restrict__ nelist,
                          const float* __restrict__ egs, const float* __restrict__ scal,
                          const float* __restrict__ xhat, const float* __restrict__ xnorm,
                          float* __restrict__ z) {
  __shared__ unsigned short elds[MAXNE];
  __shared__ unsigned long long wpart[4][32];
  __shared__ unsigned short list[2048];
  __shared__ int cnt_s;
  __shared__ float sred[4];
  int k = blockIdx.y, n = blockIdx.x, t = threadIdx.x;
  float g = scal[12 + k];
  if (g <= 0.f) { if (t == 0) z[k * NN + n] = 0.f; return; }
  int ec = ncnt[k * NN + n]; if (ec > MAXNE) ec = MAXNE;
  if (t < ec) elds[t] = nelist[((size_t)(k * NN + n)) * MAXNE + t];
  if (t == 0) cnt_s = 0;
  __syncthreads();
  int lane = t & 63, wv = t >> 6;
  int word = lane & 31, half = lane >> 5;
  unsigned long long acc = 0;
  for (int it = wv * 2 + half; it < ec; it += 8) {
    int e = (int)elds[it];
    float s = egs[k * EE + e];
    if (s > 0.f) acc |= emask[((size_t)(k * EE + e)) * 32 + word];
  }
  { // combine halves within wave
    unsigned int lo = (unsigned)acc, hi = (unsigned)(acc >> 32);
    unsigned int lo2 = (unsigned)__shfl_xor((int)lo, 32, 64);
    unsigned int hi2 = (unsigned)__shfl_xor((int)hi, 32, 64);
    acc |= ((unsigned long long)hi2 << 32) | lo2;
  }
  if (lane < 32) wpart[wv][lane] = acc;
  __syncthreads();
  if (t < 32) {
    unsigned long long w = wpart[0][t] | wpart[1][t] | wpart[2][t] | wpart[3][t];
    if (t == (n >> 6)) w &= ~(1ULL << (n & 63));
    int c = __popcll(w);
    if (c > 0) {
      int base = atomicAdd(&cnt_s, c);
      while (w) {
        int b = __builtin_ctzll(w); w &= w - 1;
        list[base++] = (unsigned short)((t << 6) + b);
      }
    }
  }
  __syncthreads();
  int cnt = cnt_s;
  if (cnt == 0) { if (t == 0) z[k * NN + n] = 0.f; return; }
  int fc = lane & 31, hh = lane >> 5;
  float4 xn4 = ((const float4*)xhat)[(size_t)n * 32 + fc];
  float a = 0.f;
  for (int it = wv * 2 + hh; it < cnt; it += 8) {
    int m = (int)list[it];
    float4 xm = ((const float4*)xhat)[(size_t)m * 32 + fc];
    a += xn4.x * xm.x + xn4.y * xm.y + xn4.z * xm.z + xn4.w * xm.w;
  }
  for (int o = 32; o > 0; o >>= 1) a += __shfl_xor(a, o, 64);
  if (lane == 0) sred[wv] = a;
  __syncthreads();
  if (t == 0) {
    float s = sred[0] + sred[1] + sred[2] + sred[3];
    z[k * NN + n] = (s / (float)cnt) * xnorm[n];
  }
}

// ---------- npi = softmax(z) per k ----------
__global__ void k_npi(const float* __restrict__ z, float* __restrict__ out_npi) {
  __shared__ float red[4];
  int k = blockIdx.x, t = threadIdx.x;
  float v[8]; float m = -1e30f;
#pragma unroll
  for (int j = 0; j < 8; j++) { v[j] = z[k * NN + t + j * 256]; m = fmaxf(m, v[j]); }
  for (int o = 32; o > 0; o >>= 1) m = fmaxf(m, __shfl_xor(m, o, 64));
  if ((t & 63) == 0) red[t >> 6] = m;
  __syncthreads();
  m = fmaxf(fmaxf(red[0], red[1]), fmaxf(red[2], red[3]));
  __syncthreads();
  float pe[8]; float s = 0.f;
#pragma unroll
  for (int j = 0; j < 8; j++) { pe[j] = expf(v[j] - m); s += pe[j]; }
  for (int o = 32; o > 0; o >>= 1) s += __shfl_xor(s, o, 64);
  if ((t & 63) == 0) red[t >> 6] = s;
  __syncthreads();
  s = red[0] + red[1] + red[2] + red[3];
#pragma unroll
  for (int j = 0; j < 8; j++) out_npi[k * NN + t + j * 256] = pe[j] / s;
}

extern "C" void kernel_launch(void* const* d_in, const int* in_sizes, int n_in,
                              void* d_out, int out_size, void* d_ws, size_t ws_size,
                              hipStream_t stream) {
  const float* H     = (const float*)d_in[0];
  const float* X     = (const float*)d_in[1];
  const int*   epoch = (const int*)d_in[2];
  const float* w1    = (const float*)d_in[3];
  const float* b1    = (const float*)d_in[4];
  const float* w2    = (const float*)d_in[5];
  const float* b2    = (const float*)d_in[6];
  const float* compW = (const float*)d_in[7];
  const float* aw1   = (const float*)d_in[8];
  const float* ab1   = (const float*)d_in[9];
  const float* aw2   = (const float*)d_in[10];
  const float* ab2   = (const float*)d_in[11];

  char* ws = (char*)d_ws;
  float* xhat  = (float*)(ws + OFF_XHAT);
  float* xnorm = (float*)(ws + OFF_XNORM);
  float* scal  = (float*)(ws + OFF_SCAL);
  int*   ncnt  = (int*)(ws + OFF_NCNT);
  unsigned long long* emask = (unsigned long long*)(ws + OFF_EMASK);
  unsigned short* nelist = (unsigned short*)(ws + OFF_NELIST);
  float* egs   = (float*)(ws + OFF_EGS);
  float* zbuf  = (float*)(ws + OFF_Z);

  float* out       = (float*)d_out;
  float* out_gates = out + (size_t)KCOMP * NN * EE;
  float* out_eg    = out_gates + KCOMP;
  float* out_npi   = out_eg + (size_t)KCOMP * EE;

  // zero scal + ncnt only (emask fully overwritten by k_scan; d_out fully written by k_hp)
  hipMemsetAsync(ws + OFF_SCAL, 0, 256 + 32768, stream);

  k_scan<<<KCOMP * 32 * (EE / 4) / 256, 256, 0, stream>>>((const float4*)H, emask, ncnt, nelist);
  k_xhat<<<NN * 64 / 256, 256, 0, stream>>>(X, xhat, xnorm);
  k_mlp<<<dim3(NN / 16, KCOMP), 256, 0, stream>>>(X, w1, b1, w2, b2, aw1, ab1, aw2, ab2, scal);
  k_gates<<<1, 256, 0, stream>>>(compW, scal, epoch, out_gates);
  k_edgegate<<<KCOMP, 1024, 0, stream>>>(emask, xhat, scal, egs, out_eg);
  k_hp<<<dim3(NN, KCOMP), 256, 0, stream>>>(ncnt, nelist, egs, out);
  k_rowscan<<<dim3(NN, KCOMP), 256, 0, stream>>>(emask, ncnt, nelist, egs, scal, xhat, xnorm, zbuf);
  k_npi<<<KCOMP, 256, 0, stream>>>(zbuf, out_npi);
}

// Round 5
// 481.406 us; speedup vs baseline: 1.1968x; 1.1968x over previous
//
#include <hip/hip_runtime.h>
#include <math.h>

#define KCOMP 4
#define NN 2048
#define EE 4096
#define DD 128
#define MAXNE 96
#define MAXSE 500
#define BETA_C 0.6f
#define EPS_G 0.01f
#define LAM_S 0.05f
#define TC0_C 0.3f
#define TCMAX_C 0.7f
#define COS_EPS_C 1e-8f

// ---- workspace layout (bytes) ----
static const size_t OFF_XHAT   = 0;          // N*D f32 = 1 MB
static const size_t OFF_XNORM  = 1048576;    // N f32 = 8 KB
static const size_t OFF_SCAL   = 1056768;    // 256 B
static const size_t OFF_NCNT   = 1057024;    // K*N i32 = 32 KB (fully written by k_nelist)
static const size_t OFF_EMASK  = 1089792;    // K*E*64 u32 = 4 MB (fully written by k_scan)
static const size_t OFF_NELIST = 5284096;    // K*N*96 u16 = 1.5 MB
static const size_t OFF_IMPE   = 6856960;    // K*512 f32 = 8 KB
static const size_t OFF_EGS    = 6865152;    // K*E f32 = 64 KB (gates[k]*eg_eff[e])
static const size_t OFF_Z      = 6930688;    // K*N f32 = 32 KB

// ---------- xhat / xnorm : wave per node ----------
__global__ void k_xhat(const float* __restrict__ X, float* __restrict__ xhat,
                       float* __restrict__ xnorm) {
  int wid  = (blockIdx.x * blockDim.x + threadIdx.x) >> 6;
  int lane = threadIdx.x & 63;
  if (wid >= NN) return;
  float2 v = ((const float2*)X)[(size_t)wid * 64 + lane];
  float ss = v.x * v.x + v.y * v.y;
  for (int o = 32; o > 0; o >>= 1) ss += __shfl_xor(ss, o, 64);
  float nrm = sqrtf(ss);
  float den = fmaxf(nrm, COS_EPS_C);
  if (lane == 0) xnorm[wid] = nrm;
  float2 o2; o2.x = v.x / den; o2.y = v.y / den;
  ((float2*)xhat)[(size_t)wid * 64 + lane] = o2;
}

// ---------- pure streaming H scan -> per-edge u32 member-mask words ----------
// thread owns (k, ch in [0,64), e4): 32 rows x 4 edges; branchless, batch-8 loads.
__global__ void k_scan(const float4* __restrict__ H4, unsigned* __restrict__ emask) {
  int gid = blockIdx.x * blockDim.x + threadIdx.x;   // [k][ch][e4]
  int e4 = gid & (EE / 4 - 1);
  int rest = gid >> 10;
  int ch = rest & 63;
  int k  = rest >> 6;
  int n0 = ch * 32;
  const float4* p = H4 + ((size_t)k * NN + n0) * (EE / 4) + e4;
  unsigned w0 = 0, w1 = 0, w2 = 0, w3 = 0;
  for (int rb = 0; rb < 32; rb += 8) {
    float4 v[8];
#pragma unroll
    for (int u = 0; u < 8; ++u) v[u] = p[(size_t)(rb + u) * (EE / 4)];
#pragma unroll
    for (int u = 0; u < 8; ++u) {
      unsigned bit = 1u << (rb + u);
      w0 |= (v[u].x > 0.f) ? bit : 0u;
      w1 |= (v[u].y > 0.f) ? bit : 0u;
      w2 |= (v[u].z > 0.f) ? bit : 0u;
      w3 |= (v[u].w > 0.f) ? bit : 0u;
    }
  }
  size_t base = ((size_t)(k * EE) + e4 * 4) * 64 + ch;
  emask[base]       = w0;
  emask[base + 64]  = w1;
  emask[base + 128] = w2;
  emask[base + 192] = w3;
}

// ---------- transpose emask -> node->edge lists; block per (k, word w) = 32 nodes ----------
__global__ void k_nelist(const unsigned* __restrict__ emask, int* __restrict__ ncnt,
                         unsigned short* __restrict__ nelist) {
  __shared__ unsigned short lst[32][MAXNE];
  __shared__ int lcnt[32];
  int k = blockIdx.y, w = blockIdx.x, t = threadIdx.x;
  if (t < 32) lcnt[t] = 0;
  __syncthreads();
  for (int e = t; e < EE; e += 256) {
    unsigned wd = emask[((size_t)(k * EE) + e) * 64 + w];
    while (wd) {
      int b = __builtin_ctz(wd); wd &= wd - 1;
      int slot = atomicAdd(&lcnt[b], 1);
      if (slot < MAXNE) lst[b][slot] = (unsigned short)e;
    }
  }
  __syncthreads();
  if (t < 32) ncnt[k * NN + w * 32 + t] = lcnt[t];
  for (int i = t; i < 32 * MAXNE; i += 256) {
    int b = i / MAXNE, s = i - b * MAXNE;
    int c = lcnt[b]; if (c > MAXNE) c = MAXNE;
    if (s < c) nelist[((size_t)(k * NN + w * 32 + b)) * MAXNE + s] = lst[b][s];
  }
}

// ---------- fused MLP chain, 16-node tiles ----------
__global__ void k_mlp(const float* __restrict__ X,
                      const float* __restrict__ w1, const float* __restrict__ b1,
                      const float* __restrict__ w2, const float* __restrict__ b2,
                      const float* __restrict__ aw1, const float* __restrict__ ab1,
                      const float* __restrict__ aw2, const float* __restrict__ ab2,
                      float* __restrict__ scal) {
  __shared__ float Xs[16 * 128];
  __shared__ float H1s[16 * 128];
  __shared__ float XKs[16 * 128];
  __shared__ float A1s[16 * 64];
  __shared__ float red[16];
  int t = threadIdx.x;
  int k = blockIdx.y;
  int n0 = blockIdx.x * 16;
  for (int i = t; i < 16 * 128; i += 256) Xs[i] = X[(size_t)n0 * 128 + i];
  __syncthreads();

  int h = t & 127, g = t >> 7;
  const float* W1 = w1 + (size_t)k * 128 * 128;
  float acc[8];
  float bb = b1[k * 128 + h];
#pragma unroll
  for (int i = 0; i < 8; i++) acc[i] = bb;
  for (int d = 0; d < 128; ++d) {
    float w = W1[d * 128 + h];
#pragma unroll
    for (int i = 0; i < 8; i++) acc[i] = fmaf(Xs[(g * 8 + i) * 128 + d], w, acc[i]);
  }
#pragma unroll
  for (int i = 0; i < 8; i++) H1s[(g * 8 + i) * 128 + h] = fmaxf(acc[i], 0.f);
  __syncthreads();

  const float* W2 = w2 + (size_t)k * 128 * 128;
  bb = b2[k * 128 + h];
#pragma unroll
  for (int i = 0; i < 8; i++) acc[i] = bb;
  for (int d = 0; d < 128; ++d) {
    float w = W2[d * 128 + h];
#pragma unroll
    for (int i = 0; i < 8; i++) acc[i] = fmaf(H1s[(g * 8 + i) * 128 + d], w, acc[i]);
  }
  float fpart = 0.f;
#pragma unroll
  for (int i = 0; i < 8; i++) { XKs[(g * 8 + i) * 128 + h] = acc[i]; fpart = fmaf(acc[i], acc[i], fpart); }
  __syncthreads();

  int h2 = t & 63, g4 = t >> 6;
  const float* AW1 = aw1 + (size_t)k * 128 * 64;
  float a4[4];
  float ab = ab1[k * 64 + h2];
#pragma unroll
  for (int i = 0; i < 4; i++) a4[i] = ab;
  for (int d = 0; d < 128; ++d) {
    float w = AW1[d * 64 + h2];
#pragma unroll
    for (int i = 0; i < 4; i++) a4[i] = fmaf(XKs[(g4 * 4 + i) * 128 + d], w, a4[i]);
  }
#pragma unroll
  for (int i = 0; i < 4; i++) A1s[(g4 * 4 + i) * 64 + h2] = fmaxf(a4[i], 0.f);
  __syncthreads();

  float attsum = 0.f;
  if (t < 16) {
    const float* AW2 = aw2 + (size_t)k * 64;
    float a = ab2[k];
    for (int d = 0; d < 64; ++d) a = fmaf(A1s[t * 64 + d], AW2[d], a);
    attsum = 1.f / (1.f + expf(-a));
  }
  for (int o = 32; o > 0; o >>= 1) {
    fpart  += __shfl_xor(fpart, o, 64);
    attsum += __shfl_xor(attsum, o, 64);
  }
  int wv = t >> 6, ln = t & 63;
  if (ln == 0) { red[wv] = fpart; red[8 + wv] = attsum; }
  __syncthreads();
  if (t == 0) {
    float fs = red[0] + red[1] + red[2] + red[3];
    float as = red[8] + red[9] + red[10] + red[11];
    atomicAdd(&scal[0 + k], fs);
    atomicAdd(&scal[4 + k], as);
  }
}

// ---------- component gates (frobenius fused in), one block ----------
__global__ void k_gates(const float* __restrict__ W, float* __restrict__ scal,
                        const int* __restrict__ epoch, float* __restrict__ out_gates) {
  __shared__ float fro[4];
  int t = threadIdx.x, k = t >> 6, lane = t & 63;
  const float* p = W + (size_t)k * 16384;
  float s = 0.f;
  for (int i = lane; i < 16384; i += 64) { float v = p[i]; s = fmaf(v, v, s); }
  for (int o = 32; o > 0; o >>= 1) s += __shfl_xor(s, o, 64);
  if (lane == 0) fro[k] = s;
  __syncthreads();
  if (t != 0) return;
  float imp[KCOMP];
  for (int kk = 0; kk < KCOMP; kk++) {
    float featn = sqrtf(scal[0 + kk]);
    float satt  = scal[4 + kk] / (float)NN;
    float frob  = sqrtf(fro[kk]);
    imp[kk] = BETA_C * frob * featn + (1.f - BETA_C) * satt;
  }
  float m = imp[0];
  for (int kk = 1; kk < KCOMP; kk++) m = fmaxf(m, imp[kk]);
  float ex[KCOMP], ssum = 0.f;
  for (int kk = 0; kk < KCOMP; kk++) { ex[kk] = expf(imp[kk] - m); ssum += ex[kk]; }
  float tc = TC0_C + (1.f - expf(-LAM_S * (float)epoch[0])) * (TCMAX_C - TC0_C);
  float gates[KCOMP];
  for (int kk = 0; kk < KCOMP; kk++) {
    float pi = ex[kk] / ssum;
    gates[kk] = fminf(fmaxf((pi - tc) / EPS_G + 0.5f, 0.f), 1.f);
  }
  int am = 0; float bv = gates[0];
  for (int kk = 1; kk < KCOMP; kk++) if (gates[kk] > bv) { bv = gates[kk]; am = kk; }
  gates[am] = fmaxf(gates[am], 1.f);
  for (int kk = 0; kk < KCOMP; kk++) { scal[12 + kk] = gates[kk]; out_gates[kk] = gates[kk]; }
  scal[16] = tc;
}

// ---------- per-edge cosine importance, wave per edge (500 parallel waves) ----------
// H binary -> A_ij = 1; i,j = two lowest member indices (matches argmax semantics).
__global__ void k_cosimp(const unsigned* __restrict__ emask, const float* __restrict__ xhat,
                         float* __restrict__ impE) {
  int k = blockIdx.y;
  int e = blockIdx.x * 4 + (threadIdx.x >> 6);
  int lane = threadIdx.x & 63;
  unsigned w = emask[((size_t)(k * EE) + e) * 64 + lane];
  int pc = __popc(w);
  for (int o = 32; o > 0; o >>= 1) pc += __shfl_xor(pc, o, 64);
  float impv = 0.1f;
  if (pc >= 2) {
    unsigned l1 = w ? (unsigned)((lane << 5) + __builtin_ctz(w)) : 0xffffffffu;
    unsigned wr = w & (w - 1);
    unsigned l2 = wr ? (unsigned)((lane << 5) + __builtin_ctz(wr)) : 0xffffffffu;
    unsigned g1 = l1;
    for (int o = 32; o > 0; o >>= 1) {
      unsigned x = (unsigned)__shfl_xor((int)g1, o, 64);
      g1 = g1 < x ? g1 : x;
    }
    unsigned cand = (l1 == g1) ? l2 : l1;
    unsigned g2 = cand;
    for (int o = 32; o > 0; o >>= 1) {
      unsigned x = (unsigned)__shfl_xor((int)g2, o, 64);
      g2 = g2 < x ? g2 : x;
    }
    float2 xi = ((const float2*)xhat)[(size_t)g1 * 64 + lane];
    float2 xj = ((const float2*)xhat)[(size_t)g2 * 64 + lane];
    float d = xi.x * xj.x + xi.y * xj.y;
    for (int o = 32; o > 0; o >>= 1) d += __shfl_xor(d, o, 64);
    impv = d;
  }
  if (lane == 0) impE[k * 512 + e] = impv;
}

// ---------- edge softmax + gating, one block per k ----------
__device__ __forceinline__ float blockReduceSum16(float v, float* red, int t) {
  for (int o = 32; o > 0; o >>= 1) v += __shfl_xor(v, o, 64);
  __syncthreads();
  if ((t & 63) == 0) red[t >> 6] = v;
  __syncthreads();
  float s = red[0];
#pragma unroll
  for (int i = 1; i < 16; i++) s += red[i];
  return s;
}

__global__ void k_edgegate(const float* __restrict__ impE, const float* __restrict__ scal,
                           float* __restrict__ egscaled, float* __restrict__ out_eg) {
  __shared__ float red[16];
  __shared__ int redi[16];
  int k = blockIdx.x;
  int t = threadIdx.x;
  float imp[4];
#pragma unroll
  for (int j = 0; j < 4; j++) {
    int e = t + j * 1024;
    imp[j] = (e < MAXSE) ? impE[k * 512 + e] : 0.f;
  }
  float m = fmaxf(fmaxf(imp[0], imp[1]), fmaxf(imp[2], imp[3]));
  for (int o = 32; o > 0; o >>= 1) m = fmaxf(m, __shfl_xor(m, o, 64));
  __syncthreads();
  if ((t & 63) == 0) red[t >> 6] = m;
  __syncthreads();
  m = red[0];
#pragma unroll
  for (int i = 1; i < 16; i++) m = fmaxf(m, red[i]);
  float p[4], psum = 0.f;
#pragma unroll
  for (int j = 0; j < 4; j++) { p[j] = expf(imp[j] - m); psum += p[j]; }
  float S = blockReduceSum16(psum, red, t);
  float pi[4], tot = 0.f;
#pragma unroll
  for (int j = 0; j < 4; j++) { pi[j] = p[j] / S; tot += pi[j]; }
  float T = blockReduceSum16(tot, red, t);
  float mean = T / (float)EE;
  float devs = 0.f;
#pragma unroll
  for (int j = 0; j < 4; j++) { float d = pi[j] - mean; devs = fmaf(d, d, devs); }
  float V = blockReduceSum16(devs, red, t);
  float stdv = sqrtf(V / (float)(EE - 1));
  float theta = fminf(scal[16], mean + stdv);
  float eg[4], egsum = 0.f;
#pragma unroll
  for (int j = 0; j < 4; j++) {
    eg[j] = fminf(fmaxf((pi[j] - theta) / EPS_G + 0.5f, 0.f), 1.f);
    egsum += eg[j];
  }
  float EGS = blockReduceSum16(egsum, red, t);
  float bv = -1e30f; int bi = 0x7fffffff;
#pragma unroll
  for (int j = 0; j < 4; j++) if (pi[j] > bv) { bv = pi[j]; bi = t + j * 1024; }
  for (int o = 32; o > 0; o >>= 1) {
    float ov = __shfl_xor(bv, o, 64); int oi = __shfl_xor(bi, o, 64);
    if (ov > bv || (ov == bv && oi < bi)) { bv = ov; bi = oi; }
  }
  __syncthreads();
  if ((t & 63) == 0) { red[t >> 6] = bv; redi[t >> 6] = bi; }
  __syncthreads();
  float abv = red[0]; int abi = redi[0];
#pragma unroll
  for (int i = 1; i < 16; i++) {
    float ov = red[i]; int oi = redi[i];
    if (ov > abv || (ov == abv && oi < abi)) { abv = ov; abi = oi; }
  }
  float g = scal[12 + k];
#pragma unroll
  for (int j = 0; j < 4; j++) {
    int e = t + j * 1024;
    float egv = eg[j];
    if (EGS < 1.f && e == abi) egv = 1.f;
    out_eg[(size_t)k * EE + e] = egv;
    float eff = (g > 0.5f) ? egv : 1.f;
    egscaled[k * EE + e] = g * eff;
  }
}

// ---------- Hp: compose each output row in LDS, stream out dense ----------
__global__ void k_hp(const int* __restrict__ ncnt, const unsigned short* __restrict__ nelist,
                     const float* __restrict__ egs, float* __restrict__ out) {
  __shared__ float row[EE];
  int k = blockIdx.y, n = blockIdx.x, t = threadIdx.x;
  float4* row4 = (float4*)row;
  float4 z4 = {0.f, 0.f, 0.f, 0.f};
#pragma unroll
  for (int i = 0; i < 4; i++) row4[t + i * 256] = z4;
  __syncthreads();
  int ec = ncnt[k * NN + n]; if (ec > MAXNE) ec = MAXNE;
  if (t < ec) {
    int e = nelist[((size_t)(k * NN + n)) * MAXNE + t];
    row[e] = egs[k * EE + e];
  }
  __syncthreads();
  float4* o4 = (float4*)(out + ((size_t)(k * NN + n)) * EE);
#pragma unroll
  for (int i = 0; i < 4; i++) o4[t + i * 256] = row4[t + i * 256];
}

// ---------- fused adjacency-build + row scan: block per (n,k) ----------
__global__ void k_rowscan(const unsigned* __restrict__ emask,
                          const int* __restrict__ ncnt, const unsigned short* __restrict__ nelist,
                          const float* __restrict__ egs, const float* __restrict__ scal,
                          const float* __restrict__ xhat, const float* __restrict__ xnorm,
                          float* __restrict__ z) {
  __shared__ unsigned short elds[MAXNE];
  __shared__ unsigned wpart[4][64];
  __shared__ unsigned short list[2048];
  __shared__ int cnt_s;
  __shared__ float sred[4];
  int k = blockIdx.y, n = blockIdx.x, t = threadIdx.x;
  float g = scal[12 + k];
  if (g <= 0.f) { if (t == 0) z[k * NN + n] = 0.f; return; }
  int ec = ncnt[k * NN + n]; if (ec > MAXNE) ec = MAXNE;
  if (t < ec) elds[t] = nelist[((size_t)(k * NN + n)) * MAXNE + t];
  if (t == 0) cnt_s = 0;
  __syncthreads();
  int lane = t & 63, wv = t >> 6;
  unsigned acc = 0;
  for (int it = wv; it < ec; it += 4) {
    int e = (int)elds[it];
    float s = egs[k * EE + e];
    if (s > 0.f) acc |= emask[((size_t)(k * EE) + e) * 64 + lane];
  }
  wpart[wv][lane] = acc;
  __syncthreads();
  if (t < 64) {
    unsigned w = wpart[0][t] | wpart[1][t] | wpart[2][t] | wpart[3][t];
    if (t == (n >> 5)) w &= ~(1u << (n & 31));
    int c = __popc(w);
    if (c > 0) {
      int base = atomicAdd(&cnt_s, c);
      while (w) {
        int b = __builtin_ctz(w); w &= w - 1;
        list[base++] = (unsigned short)((t << 5) + b);
      }
    }
  }
  __syncthreads();
  int cnt = cnt_s;
  if (cnt == 0) { if (t == 0) z[k * NN + n] = 0.f; return; }
  int fc = lane & 31, hh = lane >> 5;
  float4 xn4 = ((const float4*)xhat)[(size_t)n * 32 + fc];
  float a = 0.f;
  for (int it = wv * 2 + hh; it < cnt; it += 8) {
    int m = (int)list[it];
    float4 xm = ((const float4*)xhat)[(size_t)m * 32 + fc];
    a += xn4.x * xm.x + xn4.y * xm.y + xn4.z * xm.z + xn4.w * xm.w;
  }
  for (int o = 32; o > 0; o >>= 1) a += __shfl_xor(a, o, 64);
  if (lane == 0) sred[wv] = a;
  __syncthreads();
  if (t == 0) {
    float s = sred[0] + sred[1] + sred[2] + sred[3];
    z[k * NN + n] = (s / (float)cnt) * xnorm[n];
  }
}

// ---------- npi = softmax(z) per k ----------
__global__ void k_npi(const float* __restrict__ z, float* __restrict__ out_npi) {
  __shared__ float red[4];
  int k = blockIdx.x, t = threadIdx.x;
  float v[8]; float m = -1e30f;
#pragma unroll
  for (int j = 0; j < 8; j++) { v[j] = z[k * NN + t + j * 256]; m = fmaxf(m, v[j]); }
  for (int o = 32; o > 0; o >>= 1) m = fmaxf(m, __shfl_xor(m, o, 64));
  if ((t & 63) == 0) red[t >> 6] = m;
  __syncthreads();
  m = fmaxf(fmaxf(red[0], red[1]), fmaxf(red[2], red[3]));
  __syncthreads();
  float pe[8]; float s = 0.f;
#pragma unroll
  for (int j = 0; j < 8; j++) { pe[j] = expf(v[j] - m); s += pe[j]; }
  for (int o = 32; o > 0; o >>= 1) s += __shfl_xor(s, o, 64);
  if ((t & 63) == 0) red[t >> 6] = s;
  __syncthreads();
  s = red[0] + red[1] + red[2] + red[3];
#pragma unroll
  for (int j = 0; j < 8; j++) out_npi[k * NN + t + j * 256] = pe[j] / s;
}

extern "C" void kernel_launch(void* const* d_in, const int* in_sizes, int n_in,
                              void* d_out, int out_size, void* d_ws, size_t ws_size,
                              hipStream_t stream) {
  const float* H     = (const float*)d_in[0];
  const float* X     = (const float*)d_in[1];
  const int*   epoch = (const int*)d_in[2];
  const float* w1    = (const float*)d_in[3];
  const float* b1    = (const float*)d_in[4];
  const float* w2    = (const float*)d_in[5];
  const float* b2    = (const float*)d_in[6];
  const float* compW = (const float*)d_in[7];
  const float* aw1   = (const float*)d_in[8];
  const float* ab1   = (const float*)d_in[9];
  const float* aw2   = (const float*)d_in[10];
  const float* ab2   = (const float*)d_in[11];

  char* ws = (char*)d_ws;
  float* xhat  = (float*)(ws + OFF_XHAT);
  float* xnorm = (float*)(ws + OFF_XNORM);
  float* scal  = (float*)(ws + OFF_SCAL);
  int*   ncnt  = (int*)(ws + OFF_NCNT);
  unsigned* emask = (unsigned*)(ws + OFF_EMASK);
  unsigned short* nelist = (unsigned short*)(ws + OFF_NELIST);
  float* impE  = (float*)(ws + OFF_IMPE);
  float* egs   = (float*)(ws + OFF_EGS);
  float* zbuf  = (float*)(ws + OFF_Z);

  float* out       = (float*)d_out;
  float* out_gates = out + (size_t)KCOMP * NN * EE;
  float* out_eg    = out_gates + KCOMP;
  float* out_npi   = out_eg + (size_t)KCOMP * EE;

  // zero scal only (emask/ncnt/nelist fully written; d_out fully written by k_hp)
  hipMemsetAsync(ws + OFF_SCAL, 0, 256, stream);

  k_scan<<<KCOMP * 64 * (EE / 4) / 256, 256, 0, stream>>>((const float4*)H, emask);
  k_xhat<<<NN * 64 / 256, 256, 0, stream>>>(X, xhat, xnorm);
  k_mlp<<<dim3(NN / 16, KCOMP), 256, 0, stream>>>(X, w1, b1, w2, b2, aw1, ab1, aw2, ab2, scal);
  k_nelist<<<dim3(64, KCOMP), 256, 0, stream>>>(emask, ncnt, nelist);
  k_gates<<<1, 256, 0, stream>>>(compW, scal, epoch, out_gates);
  k_cosimp<<<dim3(125, KCOMP), 256, 0, stream>>>(emask, xhat, impE);
  k_edgegate<<<KCOMP, 1024, 0, stream>>>(impE, scal, egs, out_eg);
  k_hp<<<dim3(NN, KCOMP), 256, 0, stream>>>(ncnt, nelist, egs, out);
  k_rowscan<<<dim3(NN, KCOMP), 256, 0, stream>>>(emask, ncnt, nelist, egs, scal, xhat, xnorm, zbuf);
  k_npi<<<KCOMP, 256, 0, stream>>>(zbuf, out_npi);
}

// Round 6
// 384.567 us; speedup vs baseline: 1.4982x; 1.2518x over previous
//
#include <hip/hip_runtime.h>
#include <math.h>

#define KCOMP 4
#define NN 2048
#define EE 4096
#define DD 128
#define MAXNE 96
#define MAXSE 500
#define BETA_C 0.6f
#define EPS_G 0.01f
#define LAM_S 0.05f
#define TC0_C 0.3f
#define TCMAX_C 0.7f
#define COS_EPS_C 1e-8f

// ---- workspace layout (bytes) ----
static const size_t OFF_XHAT   = 0;          // N*D f32 = 1 MB
static const size_t OFF_XNORM  = 1048576;    // N f32 = 8 KB
static const size_t OFF_SCAL   = 1056768;    // 256 B
static const size_t OFF_NCNT   = 1057024;    // K*N i32 = 32 KB (fully written by k_nelist)
static const size_t OFF_EMASK  = 1089792;    // K*E*64 u32 = 4 MB (fully written by k_scan)
static const size_t OFF_NELIST = 5284096;    // K*N*96 u16 = 1.5 MB
static const size_t OFF_IMPE   = 6856960;    // K*512 f32 = 8 KB
static const size_t OFF_EGS    = 6865152;    // K*E f32 = 64 KB (gates[k]*eg_eff[e])
static const size_t OFF_Z      = 6930688;    // K*N f32 = 32 KB

// ---------- xhat / xnorm : wave per node ----------
__global__ void k_xhat(const float* __restrict__ X, float* __restrict__ xhat,
                       float* __restrict__ xnorm) {
  int wid  = (blockIdx.x * blockDim.x + threadIdx.x) >> 6;
  int lane = threadIdx.x & 63;
  if (wid >= NN) return;
  float2 v = ((const float2*)X)[(size_t)wid * 64 + lane];
  float ss = v.x * v.x + v.y * v.y;
  for (int o = 32; o > 0; o >>= 1) ss += __shfl_xor(ss, o, 64);
  float nrm = sqrtf(ss);
  float den = fmaxf(nrm, COS_EPS_C);
  if (lane == 0) xnorm[wid] = nrm;
  float2 o2; o2.x = v.x / den; o2.y = v.y / den;
  ((float2*)xhat)[(size_t)wid * 64 + lane] = o2;
}

// ---------- pure streaming H scan -> per-edge u32 member-mask words ----------
__global__ void k_scan(const float4* __restrict__ H4, unsigned* __restrict__ emask) {
  int gid = blockIdx.x * blockDim.x + threadIdx.x;   // [k][ch][e4]
  int e4 = gid & (EE / 4 - 1);
  int rest = gid >> 10;
  int ch = rest & 63;
  int k  = rest >> 6;
  int n0 = ch * 32;
  const float4* p = H4 + ((size_t)k * NN + n0) * (EE / 4) + e4;
  unsigned w0 = 0, w1 = 0, w2 = 0, w3 = 0;
  for (int rb = 0; rb < 32; rb += 8) {
    float4 v[8];
#pragma unroll
    for (int u = 0; u < 8; ++u) v[u] = p[(size_t)(rb + u) * (EE / 4)];
#pragma unroll
    for (int u = 0; u < 8; ++u) {
      unsigned bit = 1u << (rb + u);
      w0 |= (v[u].x > 0.f) ? bit : 0u;
      w1 |= (v[u].y > 0.f) ? bit : 0u;
      w2 |= (v[u].z > 0.f) ? bit : 0u;
      w3 |= (v[u].w > 0.f) ? bit : 0u;
    }
  }
  size_t base = ((size_t)(k * EE) + e4 * 4) * 64 + ch;
  emask[base]       = w0;
  emask[base + 64]  = w1;
  emask[base + 128] = w2;
  emask[base + 192] = w3;
}

// ---------- transpose emask -> node->edge lists; block per (k, word w) = 32 nodes ----------
__global__ void k_nelist(const unsigned* __restrict__ emask, int* __restrict__ ncnt,
                         unsigned short* __restrict__ nelist) {
  __shared__ unsigned short lst[32][MAXNE];
  __shared__ int lcnt[32];
  int k = blockIdx.y, w = blockIdx.x, t = threadIdx.x;
  if (t < 32) lcnt[t] = 0;
  __syncthreads();
  for (int e = t; e < EE; e += 256) {
    unsigned wd = emask[((size_t)(k * EE) + e) * 64 + w];
    while (wd) {
      int b = __builtin_ctz(wd); wd &= wd - 1;
      int slot = atomicAdd(&lcnt[b], 1);
      if (slot < MAXNE) lst[b][slot] = (unsigned short)e;
    }
  }
  __syncthreads();
  if (t < 32) ncnt[k * NN + w * 32 + t] = lcnt[t];
  for (int i = t; i < 32 * MAXNE; i += 256) {
    int b = i / MAXNE, s = i - b * MAXNE;
    int c = lcnt[b]; if (c > MAXNE) c = MAXNE;
    if (s < c) nelist[((size_t)(k * NN + w * 32 + b)) * MAXNE + s] = lst[b][s];
  }
}

// ---------- fused MLP chain, 16-node tiles ----------
__global__ void k_mlp(const float* __restrict__ X,
                      const float* __restrict__ w1, const float* __restrict__ b1,
                      const float* __restrict__ w2, const float* __restrict__ b2,
                      const float* __restrict__ aw1, const float* __restrict__ ab1,
                      const float* __restrict__ aw2, const float* __restrict__ ab2,
                      float* __restrict__ scal) {
  __shared__ float Xs[16 * 128];
  __shared__ float H1s[16 * 128];
  __shared__ float XKs[16 * 128];
  __shared__ float A1s[16 * 64];
  __shared__ float red[16];
  int t = threadIdx.x;
  int k = blockIdx.y;
  int n0 = blockIdx.x * 16;
  for (int i = t; i < 16 * 128; i += 256) Xs[i] = X[(size_t)n0 * 128 + i];
  __syncthreads();

  int h = t & 127, g = t >> 7;
  const float* W1 = w1 + (size_t)k * 128 * 128;
  float acc[8];
  float bb = b1[k * 128 + h];
#pragma unroll
  for (int i = 0; i < 8; i++) acc[i] = bb;
  for (int d = 0; d < 128; ++d) {
    float w = W1[d * 128 + h];
#pragma unroll
    for (int i = 0; i < 8; i++) acc[i] = fmaf(Xs[(g * 8 + i) * 128 + d], w, acc[i]);
  }
#pragma unroll
  for (int i = 0; i < 8; i++) H1s[(g * 8 + i) * 128 + h] = fmaxf(acc[i], 0.f);
  __syncthreads();

  const float* W2 = w2 + (size_t)k * 128 * 128;
  bb = b2[k * 128 + h];
#pragma unroll
  for (int i = 0; i < 8; i++) acc[i] = bb;
  for (int d = 0; d < 128; ++d) {
    float w = W2[d * 128 + h];
#pragma unroll
    for (int i = 0; i < 8; i++) acc[i] = fmaf(H1s[(g * 8 + i) * 128 + d], w, acc[i]);
  }
  float fpart = 0.f;
#pragma unroll
  for (int i = 0; i < 8; i++) { XKs[(g * 8 + i) * 128 + h] = acc[i]; fpart = fmaf(acc[i], acc[i], fpart); }
  __syncthreads();

  int h2 = t & 63, g4 = t >> 6;
  const float* AW1 = aw1 + (size_t)k * 128 * 64;
  float a4[4];
  float ab = ab1[k * 64 + h2];
#pragma unroll
  for (int i = 0; i < 4; i++) a4[i] = ab;
  for (int d = 0; d < 128; ++d) {
    float w = AW1[d * 64 + h2];
#pragma unroll
    for (int i = 0; i < 4; i++) a4[i] = fmaf(XKs[(g4 * 4 + i) * 128 + d], w, a4[i]);
  }
#pragma unroll
  for (int i = 0; i < 4; i++) A1s[(g4 * 4 + i) * 64 + h2] = fmaxf(a4[i], 0.f);
  __syncthreads();

  float attsum = 0.f;
  if (t < 16) {
    const float* AW2 = aw2 + (size_t)k * 64;
    float a = ab2[k];
    for (int d = 0; d < 64; ++d) a = fmaf(A1s[t * 64 + d], AW2[d], a);
    attsum = 1.f / (1.f + expf(-a));
  }
  for (int o = 32; o > 0; o >>= 1) {
    fpart  += __shfl_xor(fpart, o, 64);
    attsum += __shfl_xor(attsum, o, 64);
  }
  int wv = t >> 6, ln = t & 63;
  if (ln == 0) { red[wv] = fpart; red[8 + wv] = attsum; }
  __syncthreads();
  if (t == 0) {
    float fs = red[0] + red[1] + red[2] + red[3];
    float as = red[8] + red[9] + red[10] + red[11];
    atomicAdd(&scal[0 + k], fs);
    atomicAdd(&scal[4 + k], as);
  }
}

// ---------- frobenius^2 of comp_W: grid (16,K), one float4/thread, fully parallel ----------
__global__ void k_frob(const float4* __restrict__ W4, float* __restrict__ scal) {
  __shared__ float red[4];
  int k = blockIdx.y, t = threadIdx.x;
  float4 v = W4[(size_t)k * 4096 + blockIdx.x * 256 + t];
  float s = v.x * v.x + v.y * v.y + v.z * v.z + v.w * v.w;
  for (int o = 32; o > 0; o >>= 1) s += __shfl_xor(s, o, 64);
  if ((t & 63) == 0) red[t >> 6] = s;
  __syncthreads();
  if (t == 0) atomicAdd(&scal[8 + k], red[0] + red[1] + red[2] + red[3]);
}

// ---------- component gates: tiny scalar epilogue ----------
__global__ void k_gates(float* __restrict__ scal, const int* __restrict__ epoch,
                        float* __restrict__ out_gates) {
  if (threadIdx.x != 0) return;
  float imp[KCOMP];
  for (int kk = 0; kk < KCOMP; kk++) {
    float featn = sqrtf(scal[0 + kk]);
    float satt  = scal[4 + kk] / (float)NN;
    float frob  = sqrtf(scal[8 + kk]);
    imp[kk] = BETA_C * frob * featn + (1.f - BETA_C) * satt;
  }
  float m = imp[0];
  for (int kk = 1; kk < KCOMP; kk++) m = fmaxf(m, imp[kk]);
  float ex[KCOMP], ssum = 0.f;
  for (int kk = 0; kk < KCOMP; kk++) { ex[kk] = expf(imp[kk] - m); ssum += ex[kk]; }
  float tc = TC0_C + (1.f - expf(-LAM_S * (float)epoch[0])) * (TCMAX_C - TC0_C);
  float gates[KCOMP];
  for (int kk = 0; kk < KCOMP; kk++) {
    float pi = ex[kk] / ssum;
    gates[kk] = fminf(fmaxf((pi - tc) / EPS_G + 0.5f, 0.f), 1.f);
  }
  int am = 0; float bv = gates[0];
  for (int kk = 1; kk < KCOMP; kk++) if (gates[kk] > bv) { bv = gates[kk]; am = kk; }
  gates[am] = fmaxf(gates[am], 1.f);
  for (int kk = 0; kk < KCOMP; kk++) { scal[12 + kk] = gates[kk]; out_gates[kk] = gates[kk]; }
  scal[16] = tc;
}

// ---------- per-edge cosine importance, wave per edge ----------
__global__ void k_cosimp(const unsigned* __restrict__ emask, const float* __restrict__ xhat,
                         float* __restrict__ impE) {
  int k = blockIdx.y;
  int e = blockIdx.x * 4 + (threadIdx.x >> 6);
  int lane = threadIdx.x & 63;
  unsigned w = emask[((size_t)(k * EE) + e) * 64 + lane];
  int pc = __popc(w);
  for (int o = 32; o > 0; o >>= 1) pc += __shfl_xor(pc, o, 64);
  float impv = 0.1f;
  if (pc >= 2) {
    unsigned l1 = w ? (unsigned)((lane << 5) + __builtin_ctz(w)) : 0xffffffffu;
    unsigned wr = w & (w - 1);
    unsigned l2 = wr ? (unsigned)((lane << 5) + __builtin_ctz(wr)) : 0xffffffffu;
    unsigned g1 = l1;
    for (int o = 32; o > 0; o >>= 1) {
      unsigned x = (unsigned)__shfl_xor((int)g1, o, 64);
      g1 = g1 < x ? g1 : x;
    }
    unsigned cand = (l1 == g1) ? l2 : l1;
    unsigned g2 = cand;
    for (int o = 32; o > 0; o >>= 1) {
      unsigned x = (unsigned)__shfl_xor((int)g2, o, 64);
      g2 = g2 < x ? g2 : x;
    }
    float2 xi = ((const float2*)xhat)[(size_t)g1 * 64 + lane];
    float2 xj = ((const float2*)xhat)[(size_t)g2 * 64 + lane];
    float d = xi.x * xj.x + xi.y * xj.y;
    for (int o = 32; o > 0; o >>= 1) d += __shfl_xor(d, o, 64);
    impv = d;
  }
  if (lane == 0) impE[k * 512 + e] = impv;
}

// ---------- edge softmax + gating, one block per k ----------
__device__ __forceinline__ float blockReduceSum16(float v, float* red, int t) {
  for (int o = 32; o > 0; o >>= 1) v += __shfl_xor(v, o, 64);
  __syncthreads();
  if ((t & 63) == 0) red[t >> 6] = v;
  __syncthreads();
  float s = red[0];
#pragma unroll
  for (int i = 1; i < 16; i++) s += red[i];
  return s;
}

__global__ void k_edgegate(const float* __restrict__ impE, const float* __restrict__ scal,
                           float* __restrict__ egscaled, float* __restrict__ out_eg) {
  __shared__ float red[16];
  __shared__ int redi[16];
  int k = blockIdx.x;
  int t = threadIdx.x;
  float imp[4];
#pragma unroll
  for (int j = 0; j < 4; j++) {
    int e = t + j * 1024;
    imp[j] = (e < MAXSE) ? impE[k * 512 + e] : 0.f;
  }
  float m = fmaxf(fmaxf(imp[0], imp[1]), fmaxf(imp[2], imp[3]));
  for (int o = 32; o > 0; o >>= 1) m = fmaxf(m, __shfl_xor(m, o, 64));
  __syncthreads();
  if ((t & 63) == 0) red[t >> 6] = m;
  __syncthreads();
  m = red[0];
#pragma unroll
  for (int i = 1; i < 16; i++) m = fmaxf(m, red[i]);
  float p[4], psum = 0.f;
#pragma unroll
  for (int j = 0; j < 4; j++) { p[j] = expf(imp[j] - m); psum += p[j]; }
  float S = blockReduceSum16(psum, red, t);
  float pi[4], tot = 0.f;
#pragma unroll
  for (int j = 0; j < 4; j++) { pi[j] = p[j] / S; tot += pi[j]; }
  float T = blockReduceSum16(tot, red, t);
  float mean = T / (float)EE;
  float devs = 0.f;
#pragma unroll
  for (int j = 0; j < 4; j++) { float d = pi[j] - mean; devs = fmaf(d, d, devs); }
  float V = blockReduceSum16(devs, red, t);
  float stdv = sqrtf(V / (float)(EE - 1));
  float theta = fminf(scal[16], mean + stdv);
  float eg[4], egsum = 0.f;
#pragma unroll
  for (int j = 0; j < 4; j++) {
    eg[j] = fminf(fmaxf((pi[j] - theta) / EPS_G + 0.5f, 0.f), 1.f);
    egsum += eg[j];
  }
  float EGS = blockReduceSum16(egsum, red, t);
  float bv = -1e30f; int bi = 0x7fffffff;
#pragma unroll
  for (int j = 0; j < 4; j++) if (pi[j] > bv) { bv = pi[j]; bi = t + j * 1024; }
  for (int o = 32; o > 0; o >>= 1) {
    float ov = __shfl_xor(bv, o, 64); int oi = __shfl_xor(bi, o, 64);
    if (ov > bv || (ov == bv && oi < bi)) { bv = ov; bi = oi; }
  }
  __syncthreads();
  if ((t & 63) == 0) { red[t >> 6] = bv; redi[t >> 6] = bi; }
  __syncthreads();
  float abv = red[0]; int abi = redi[0];
#pragma unroll
  for (int i = 1; i < 16; i++) {
    float ov = red[i]; int oi = redi[i];
    if (ov > abv || (ov == abv && oi < abi)) { abv = ov; abi = oi; }
  }
  float g = scal[12 + k];
#pragma unroll
  for (int j = 0; j < 4; j++) {
    int e = t + j * 1024;
    float egv = eg[j];
    if (EGS < 1.f && e == abi) egv = 1.f;
    out_eg[(size_t)k * EE + e] = egv;
    float eff = (g > 0.5f) ? egv : 1.f;
    egscaled[k * EE + e] = g * eff;
  }
}

// ---------- Hp: compose each output row in LDS, stream out dense ----------
__global__ void k_hp(const int* __restrict__ ncnt, const unsigned short* __restrict__ nelist,
                     const float* __restrict__ egs, float* __restrict__ out) {
  __shared__ float row[EE];
  int k = blockIdx.y, n = blockIdx.x, t = threadIdx.x;
  float4* row4 = (float4*)row;
  float4 z4 = {0.f, 0.f, 0.f, 0.f};
#pragma unroll
  for (int i = 0; i < 4; i++) row4[t + i * 256] = z4;
  __syncthreads();
  int ec = ncnt[k * NN + n]; if (ec > MAXNE) ec = MAXNE;
  if (t < ec) {
    int e = nelist[((size_t)(k * NN + n)) * MAXNE + t];
    row[e] = egs[k * EE + e];
  }
  __syncthreads();
  float4* o4 = (float4*)(out + ((size_t)(k * NN + n)) * EE);
#pragma unroll
  for (int i = 0; i < 4; i++) o4[t + i * 256] = row4[t + i * 256];
}

// ---------- fused adjacency-build + row scan: block per (n,k) ----------
__global__ void k_rowscan(const unsigned* __restrict__ emask,
                          const int* __restrict__ ncnt, const unsigned short* __restrict__ nelist,
                          const float* __restrict__ egs, const float* __restrict__ scal,
                          const float* __restrict__ xhat, const float* __restrict__ xnorm,
                          float* __restrict__ z) {
  __shared__ unsigned short elds[MAXNE];
  __shared__ unsigned wpart[4][64];
  __shared__ unsigned short list[2048];
  __shared__ int cnt_s;
  __shared__ float sred[4];
  int k = blockIdx.y, n = blockIdx.x, t = threadIdx.x;
  float g = scal[12 + k];
  if (g <= 0.f) { if (t == 0) z[k * NN + n] = 0.f; return; }
  int ec = ncnt[k * NN + n]; if (ec > MAXNE) ec = MAXNE;
  if (t < ec) elds[t] = nelist[((size_t)(k * NN + n)) * MAXNE + t];
  if (t == 0) cnt_s = 0;
  __syncthreads();
  int lane = t & 63, wv = t >> 6;
  unsigned acc = 0;
  for (int it = wv; it < ec; it += 4) {
    int e = (int)elds[it];
    float s = egs[k * EE + e];
    if (s > 0.f) acc |= emask[((size_t)(k * EE) + e) * 64 + lane];
  }
  wpart[wv][lane] = acc;
  __syncthreads();
  if (t < 64) {
    unsigned w = wpart[0][t] | wpart[1][t] | wpart[2][t] | wpart[3][t];
    if (t == (n >> 5)) w &= ~(1u << (n & 31));
    int c = __popc(w);
    if (c > 0) {
      int base = atomicAdd(&cnt_s, c);
      while (w) {
        int b = __builtin_ctz(w); w &= w - 1;
        list[base++] = (unsigned short)((t << 5) + b);
      }
    }
  }
  __syncthreads();
  int cnt = cnt_s;
  if (cnt == 0) { if (t == 0) z[k * NN + n] = 0.f; return; }
  int fc = lane & 31, hh = lane >> 5;
  float4 xn4 = ((const float4*)xhat)[(size_t)n * 32 + fc];
  float a = 0.f;
  for (int it = wv * 2 + hh; it < cnt; it += 8) {
    int m = (int)list[it];
    float4 xm = ((const float4*)xhat)[(size_t)m * 32 + fc];
    a += xn4.x * xm.x + xn4.y * xm.y + xn4.z * xm.z + xn4.w * xm.w;
  }
  for (int o = 32; o > 0; o >>= 1) a += __shfl_xor(a, o, 64);
  if (lane == 0) sred[wv] = a;
  __syncthreads();
  if (t == 0) {
    float s = sred[0] + sred[1] + sred[2] + sred[3];
    z[k * NN + n] = (s / (float)cnt) * xnorm[n];
  }
}

// ---------- npi = softmax(z) per k ----------
__global__ void k_npi(const float* __restrict__ z, float* __restrict__ out_npi) {
  __shared__ float red[4];
  int k = blockIdx.x, t = threadIdx.x;
  float v[8]; float m = -1e30f;
#pragma unroll
  for (int j = 0; j < 8; j++) { v[j] = z[k * NN + t + j * 256]; m = fmaxf(m, v[j]); }
  for (int o = 32; o > 0; o >>= 1) m = fmaxf(m, __shfl_xor(m, o, 64));
  if ((t & 63) == 0) red[t >> 6] = m;
  __syncthreads();
  m = fmaxf(fmaxf(red[0], red[1]), fmaxf(red[2], red[3]));
  __syncthreads();
  float pe[8]; float s = 0.f;
#pragma unroll
  for (int j = 0; j < 8; j++) { pe[j] = expf(v[j] - m); s += pe[j]; }
  for (int o = 32; o > 0; o >>= 1) s += __shfl_xor(s, o, 64);
  if ((t & 63) == 0) red[t >> 6] = s;
  __syncthreads();
  s = red[0] + red[1] + red[2] + red[3];
#pragma unroll
  for (int j = 0; j < 8; j++) out_npi[k * NN + t + j * 256] = pe[j] / s;
}

extern "C" void kernel_launch(void* const* d_in, const int* in_sizes, int n_in,
                              void* d_out, int out_size, void* d_ws, size_t ws_size,
                              hipStream_t stream) {
  const float* H     = (const float*)d_in[0];
  const float* X     = (const float*)d_in[1];
  const int*   epoch = (const int*)d_in[2];
  const float* w1    = (const float*)d_in[3];
  const float* b1    = (const float*)d_in[4];
  const float* w2    = (const float*)d_in[5];
  const float* b2    = (const float*)d_in[6];
  const float* compW = (const float*)d_in[7];
  const float* aw1   = (const float*)d_in[8];
  const float* ab1   = (const float*)d_in[9];
  const float* aw2   = (const float*)d_in[10];
  const float* ab2   = (const float*)d_in[11];

  char* ws = (char*)d_ws;
  float* xhat  = (float*)(ws + OFF_XHAT);
  float* xnorm = (float*)(ws + OFF_XNORM);
  float* scal  = (float*)(ws + OFF_SCAL);
  int*   ncnt  = (int*)(ws + OFF_NCNT);
  unsigned* emask = (unsigned*)(ws + OFF_EMASK);
  unsigned short* nelist = (unsigned short*)(ws + OFF_NELIST);
  float* impE  = (float*)(ws + OFF_IMPE);
  float* egs   = (float*)(ws + OFF_EGS);
  float* zbuf  = (float*)(ws + OFF_Z);

  float* out       = (float*)d_out;
  float* out_gates = out + (size_t)KCOMP * NN * EE;
  float* out_eg    = out_gates + KCOMP;
  float* out_npi   = out_eg + (size_t)KCOMP * EE;

  // zero scal only (emask/ncnt/nelist fully written; d_out fully written by k_hp)
  hipMemsetAsync(ws + OFF_SCAL, 0, 256, stream);

  k_scan<<<KCOMP * 64 * (EE / 4) / 256, 256, 0, stream>>>((const float4*)H, emask);
  k_frob<<<dim3(16, KCOMP), 256, 0, stream>>>((const float4*)compW, scal);
  k_xhat<<<NN * 64 / 256, 256, 0, stream>>>(X, xhat, xnorm);
  k_mlp<<<dim3(NN / 16, KCOMP), 256, 0, stream>>>(X, w1, b1, w2, b2, aw1, ab1, aw2, ab2, scal);
  k_nelist<<<dim3(64, KCOMP), 256, 0, stream>>>(emask, ncnt, nelist);
  k_gates<<<1, 64, 0, stream>>>(scal, epoch, out_gates);
  k_cosimp<<<dim3(125, KCOMP), 256, 0, stream>>>(emask, xhat, impE);
  k_edgegate<<<KCOMP, 1024, 0, stream>>>(impE, scal, egs, out_eg);
  k_hp<<<dim3(NN, KCOMP), 256, 0, stream>>>(ncnt, nelist, egs, out);
  k_rowscan<<<dim3(NN, KCOMP), 256, 0, stream>>>(emask, ncnt, nelist, egs, scal, xhat, xnorm, zbuf);
  k_npi<<<KCOMP, 256, 0, stream>>>(zbuf, out_npi);
}

// Round 7
// 373.886 us; speedup vs baseline: 1.5410x; 1.0286x over previous
//
#include <hip/hip_runtime.h>
#include <math.h>

#define KCOMP 4
#define NN 2048
#define EE 4096
#define DD 128
#define MAXNE 96
#define MAXSE 500
#define BETA_C 0.6f
#define EPS_G 0.01f
#define LAM_S 0.05f
#define TC0_C 0.3f
#define TCMAX_C 0.7f
#define COS_EPS_C 1e-8f

// ---- workspace layout (bytes) ----
static const size_t OFF_XHAT   = 0;          // N*D f32 = 1 MB
static const size_t OFF_XNORM  = 1048576;    // N f32 = 8 KB
static const size_t OFF_SCAL   = 1056768;    // 256 B (zeroed by k_scanx block 0)
static const size_t OFF_NCNT   = 1057024;    // K*N i32 = 32 KB
static const size_t OFF_EMASK  = 1089792;    // K*E*64 u32 = 4 MB (fully written)
static const size_t OFF_NELIST = 5284096;    // K*N*96 u16 = 1.5 MB
static const size_t OFF_IMPE   = 6856960;    // K*512 f32 = 8 KB
static const size_t OFF_EGS    = 6865152;    // K*E f32 = 64 KB
static const size_t OFF_Z      = 6930688;    // K*N f32 = 32 KB

// ---------- dispatch 1: contiguous-streaming H scan + xhat + scal zero ----------
// blocks [0,256): scan. block b: k=b>>6, ch=b&63 owns rows [ch*32, ch*32+32).
//   1024 threads sweep a full 16 KB row per iteration -> 512 KB contiguous per block.
// blocks [256,384): xhat, 16 nodes per block (wave per node).
__global__ __launch_bounds__(1024) void k_scanx(
    const float4* __restrict__ H4, unsigned* __restrict__ emask,
    const float* __restrict__ X, float* __restrict__ xhat, float* __restrict__ xnorm,
    float* __restrict__ scal) {
  int b = blockIdx.x, t = threadIdx.x;
  if (b == 0 && t < 64) scal[t] = 0.f;
  if (b < 256) {
    int k = b >> 6, ch = b & 63;
    int n0 = ch * 32;
    const float4* p = H4 + ((size_t)(k * NN + n0)) * (EE / 4) + t;
    unsigned w0 = 0, w1 = 0, w2 = 0, w3 = 0;
    for (int rb = 0; rb < 32; rb += 8) {
      float4 v[8];
#pragma unroll
      for (int u = 0; u < 8; ++u) v[u] = p[(size_t)(rb + u) * (EE / 4)];
#pragma unroll
      for (int u = 0; u < 8; ++u) {
        unsigned bit = 1u << (rb + u);
        w0 |= (v[u].x > 0.f) ? bit : 0u;
        w1 |= (v[u].y > 0.f) ? bit : 0u;
        w2 |= (v[u].z > 0.f) ? bit : 0u;
        w3 |= (v[u].w > 0.f) ? bit : 0u;
      }
    }
    size_t base = ((size_t)(k * EE) + t * 4) * 64 + ch;
    emask[base]       = w0;
    emask[base + 64]  = w1;
    emask[base + 128] = w2;
    emask[base + 192] = w3;
  } else {
    int node = (b - 256) * 16 + (t >> 6);
    int lane = t & 63;
    float2 v = ((const float2*)X)[(size_t)node * 64 + lane];
    float ss = v.x * v.x + v.y * v.y;
    for (int o = 32; o > 0; o >>= 1) ss += __shfl_xor(ss, o, 64);
    float nrm = sqrtf(ss);
    float den = fmaxf(nrm, COS_EPS_C);
    if (lane == 0) xnorm[node] = nrm;
    float2 o2; o2.x = v.x / den; o2.y = v.y / den;
    ((float2*)xhat)[(size_t)node * 64 + lane] = o2;
  }
}

// ---------- dispatch 2: fused MLP chain (x<128) + frobenius (x>=128) ----------
__global__ void k_mlpf(const float* __restrict__ X,
                       const float* __restrict__ w1, const float* __restrict__ b1,
                       const float* __restrict__ w2, const float* __restrict__ b2,
                       const float* __restrict__ aw1, const float* __restrict__ ab1,
                       const float* __restrict__ aw2, const float* __restrict__ ab2,
                       const float4* __restrict__ compW4, float* __restrict__ scal) {
  __shared__ float Xs[16 * 128];
  __shared__ float H1s[16 * 128];
  __shared__ float XKs[16 * 128];
  __shared__ float A1s[16 * 64];
  __shared__ float red[16];
  int t = threadIdx.x;
  int k = blockIdx.y;
  if (blockIdx.x >= 128) {   // frobenius^2 partial: 16 blocks x 256 threads x float4
    float4 v = compW4[(size_t)k * 4096 + (blockIdx.x - 128) * 256 + t];
    float s = v.x * v.x + v.y * v.y + v.z * v.z + v.w * v.w;
    for (int o = 32; o > 0; o >>= 1) s += __shfl_xor(s, o, 64);
    if ((t & 63) == 0) red[t >> 6] = s;
    __syncthreads();
    if (t == 0) atomicAdd(&scal[8 + k], red[0] + red[1] + red[2] + red[3]);
    return;
  }
  int n0 = blockIdx.x * 16;
  for (int i = t; i < 16 * 128; i += 256) Xs[i] = X[(size_t)n0 * 128 + i];
  __syncthreads();

  int h = t & 127, g = t >> 7;
  const float* W1 = w1 + (size_t)k * 128 * 128;
  float acc[8];
  float bb = b1[k * 128 + h];
#pragma unroll
  for (int i = 0; i < 8; i++) acc[i] = bb;
  for (int d = 0; d < 128; ++d) {
    float w = W1[d * 128 + h];
#pragma unroll
    for (int i = 0; i < 8; i++) acc[i] = fmaf(Xs[(g * 8 + i) * 128 + d], w, acc[i]);
  }
#pragma unroll
  for (int i = 0; i < 8; i++) H1s[(g * 8 + i) * 128 + h] = fmaxf(acc[i], 0.f);
  __syncthreads();

  const float* W2 = w2 + (size_t)k * 128 * 128;
  bb = b2[k * 128 + h];
#pragma unroll
  for (int i = 0; i < 8; i++) acc[i] = bb;
  for (int d = 0; d < 128; ++d) {
    float w = W2[d * 128 + h];
#pragma unroll
    for (int i = 0; i < 8; i++) acc[i] = fmaf(H1s[(g * 8 + i) * 128 + d], w, acc[i]);
  }
  float fpart = 0.f;
#pragma unroll
  for (int i = 0; i < 8; i++) { XKs[(g * 8 + i) * 128 + h] = acc[i]; fpart = fmaf(acc[i], acc[i], fpart); }
  __syncthreads();

  int h2 = t & 63, g4 = t >> 6;
  const float* AW1 = aw1 + (size_t)k * 128 * 64;
  float a4[4];
  float ab = ab1[k * 64 + h2];
#pragma unroll
  for (int i = 0; i < 4; i++) a4[i] = ab;
  for (int d = 0; d < 128; ++d) {
    float w = AW1[d * 64 + h2];
#pragma unroll
    for (int i = 0; i < 4; i++) a4[i] = fmaf(XKs[(g4 * 4 + i) * 128 + d], w, a4[i]);
  }
#pragma unroll
  for (int i = 0; i < 4; i++) A1s[(g4 * 4 + i) * 64 + h2] = fmaxf(a4[i], 0.f);
  __syncthreads();

  float attsum = 0.f;
  if (t < 16) {
    const float* AW2 = aw2 + (size_t)k * 64;
    float a = ab2[k];
    for (int d = 0; d < 64; ++d) a = fmaf(A1s[t * 64 + d], AW2[d], a);
    attsum = 1.f / (1.f + expf(-a));
  }
  for (int o = 32; o > 0; o >>= 1) {
    fpart  += __shfl_xor(fpart, o, 64);
    attsum += __shfl_xor(attsum, o, 64);
  }
  int wv = t >> 6, ln = t & 63;
  if (ln == 0) { red[wv] = fpart; red[8 + wv] = attsum; }
  __syncthreads();
  if (t == 0) {
    float fs = red[0] + red[1] + red[2] + red[3];
    float as = red[8] + red[9] + red[10] + red[11];
    atomicAdd(&scal[0 + k], fs);
    atomicAdd(&scal[4 + k], as);
  }
}

// ---------- dispatch 3: nelist transpose (x<64) + cosine importance (x>=64) ----------
__global__ void k_nelc(const unsigned* __restrict__ emask, int* __restrict__ ncnt,
                       unsigned short* __restrict__ nelist, const float* __restrict__ xhat,
                       float* __restrict__ impE) {
  int k = blockIdx.y, t = threadIdx.x;
  if (blockIdx.x < 64) {
    __shared__ unsigned short lst[32][MAXNE];
    __shared__ int lcnt[32];
    int w = blockIdx.x;
    if (t < 32) lcnt[t] = 0;
    __syncthreads();
    for (int e = t; e < EE; e += 256) {
      unsigned wd = emask[((size_t)(k * EE) + e) * 64 + w];
      while (wd) {
        int b = __builtin_ctz(wd); wd &= wd - 1;
        int slot = atomicAdd(&lcnt[b], 1);
        if (slot < MAXNE) lst[b][slot] = (unsigned short)e;
      }
    }
    __syncthreads();
    if (t < 32) ncnt[k * NN + w * 32 + t] = lcnt[t];
    for (int i = t; i < 32 * MAXNE; i += 256) {
      int b = i / MAXNE, s = i - b * MAXNE;
      int c = lcnt[b]; if (c > MAXNE) c = MAXNE;
      if (s < c) nelist[((size_t)(k * NN + w * 32 + b)) * MAXNE + s] = lst[b][s];
    }
    return;
  }
  // cosimp: wave per edge, e in [0,500)
  int e = (blockIdx.x - 64) * 4 + (t >> 6);
  int lane = t & 63;
  unsigned w = emask[((size_t)(k * EE) + e) * 64 + lane];
  int pc = __popc(w);
  for (int o = 32; o > 0; o >>= 1) pc += __shfl_xor(pc, o, 64);
  float impv = 0.1f;
  if (pc >= 2) {   // H binary -> A_ij = 1; i,j = two lowest member indices
    unsigned l1 = w ? (unsigned)((lane << 5) + __builtin_ctz(w)) : 0xffffffffu;
    unsigned wr = w & (w - 1);
    unsigned l2 = wr ? (unsigned)((lane << 5) + __builtin_ctz(wr)) : 0xffffffffu;
    unsigned g1 = l1;
    for (int o = 32; o > 0; o >>= 1) {
      unsigned x = (unsigned)__shfl_xor((int)g1, o, 64);
      g1 = g1 < x ? g1 : x;
    }
    unsigned cand = (l1 == g1) ? l2 : l1;
    unsigned g2 = cand;
    for (int o = 32; o > 0; o >>= 1) {
      unsigned x = (unsigned)__shfl_xor((int)g2, o, 64);
      g2 = g2 < x ? g2 : x;
    }
    float2 xi = ((const float2*)xhat)[(size_t)g1 * 64 + lane];
    float2 xj = ((const float2*)xhat)[(size_t)g2 * 64 + lane];
    float d = xi.x * xj.x + xi.y * xj.y;
    for (int o = 32; o > 0; o >>= 1) d += __shfl_xor(d, o, 64);
    impv = d;
  }
  if (lane == 0) impE[k * 512 + e] = impv;
}

// ---------- dispatch 4: edge softmax + gating; component gates computed in-block ----------
__device__ __forceinline__ float blockReduceSum16(float v, float* red, int t) {
  for (int o = 32; o > 0; o >>= 1) v += __shfl_xor(v, o, 64);
  __syncthreads();
  if ((t & 63) == 0) red[t >> 6] = v;
  __syncthreads();
  float s = red[0];
#pragma unroll
  for (int i = 1; i < 16; i++) s += red[i];
  return s;
}

__global__ void k_edgegate(const float* __restrict__ impE, float* __restrict__ scal,
                           const int* __restrict__ epoch, float* __restrict__ out_gates,
                           float* __restrict__ egscaled, float* __restrict__ out_eg) {
  __shared__ float red[16];
  __shared__ int redi[16];
  int k = blockIdx.x;
  int t = threadIdx.x;
  // --- component gates (every thread recomputes; deterministic identical) ---
  float gates[KCOMP];
  float tc;
  {
    float imp[KCOMP];
    for (int kk = 0; kk < KCOMP; kk++) {
      float featn = sqrtf(scal[0 + kk]);
      float satt  = scal[4 + kk] / (float)NN;
      float frob  = sqrtf(scal[8 + kk]);
      imp[kk] = BETA_C * frob * featn + (1.f - BETA_C) * satt;
    }
    float mx = imp[0];
    for (int kk = 1; kk < KCOMP; kk++) mx = fmaxf(mx, imp[kk]);
    float ex[KCOMP], ssum = 0.f;
    for (int kk = 0; kk < KCOMP; kk++) { ex[kk] = expf(imp[kk] - mx); ssum += ex[kk]; }
    tc = TC0_C + (1.f - expf(-LAM_S * (float)epoch[0])) * (TCMAX_C - TC0_C);
    for (int kk = 0; kk < KCOMP; kk++) {
      float pi = ex[kk] / ssum;
      gates[kk] = fminf(fmaxf((pi - tc) / EPS_G + 0.5f, 0.f), 1.f);
    }
    int am = 0; float bv2 = gates[0];
    for (int kk = 1; kk < KCOMP; kk++) if (gates[kk] > bv2) { bv2 = gates[kk]; am = kk; }
    gates[am] = fmaxf(gates[am], 1.f);
  }
  if (t == 0) {
    scal[12 + k] = gates[k];
    if (k == 0) for (int kk = 0; kk < KCOMP; kk++) out_gates[kk] = gates[kk];
  }
  // --- edge softmax ---
  float imp[4];
#pragma unroll
  for (int j = 0; j < 4; j++) {
    int e = t + j * 1024;
    imp[j] = (e < MAXSE) ? impE[k * 512 + e] : 0.f;
  }
  float m = fmaxf(fmaxf(imp[0], imp[1]), fmaxf(imp[2], imp[3]));
  for (int o = 32; o > 0; o >>= 1) m = fmaxf(m, __shfl_xor(m, o, 64));
  __syncthreads();
  if ((t & 63) == 0) red[t >> 6] = m;
  __syncthreads();
  m = red[0];
#pragma unroll
  for (int i = 1; i < 16; i++) m = fmaxf(m, red[i]);
  float p[4], psum = 0.f;
#pragma unroll
  for (int j = 0; j < 4; j++) { p[j] = expf(imp[j] - m); psum += p[j]; }
  float S = blockReduceSum16(psum, red, t);
  float pi[4], tot = 0.f;
#pragma unroll
  for (int j = 0; j < 4; j++) { pi[j] = p[j] / S; tot += pi[j]; }
  float T = blockReduceSum16(tot, red, t);
  float mean = T / (float)EE;
  float devs = 0.f;
#pragma unroll
  for (int j = 0; j < 4; j++) { float d = pi[j] - mean; devs = fmaf(d, d, devs); }
  float V = blockReduceSum16(devs, red, t);
  float stdv = sqrtf(V / (float)(EE - 1));
  float theta = fminf(tc, mean + stdv);
  float eg[4], egsum = 0.f;
#pragma unroll
  for (int j = 0; j < 4; j++) {
    eg[j] = fminf(fmaxf((pi[j] - theta) / EPS_G + 0.5f, 0.f), 1.f);
    egsum += eg[j];
  }
  float EGS = blockReduceSum16(egsum, red, t);
  float bv = -1e30f; int bi = 0x7fffffff;
#pragma unroll
  for (int j = 0; j < 4; j++) if (pi[j] > bv) { bv = pi[j]; bi = t + j * 1024; }
  for (int o = 32; o > 0; o >>= 1) {
    float ov = __shfl_xor(bv, o, 64); int oi = __shfl_xor(bi, o, 64);
    if (ov > bv || (ov == bv && oi < bi)) { bv = ov; bi = oi; }
  }
  __syncthreads();
  if ((t & 63) == 0) { red[t >> 6] = bv; redi[t >> 6] = bi; }
  __syncthreads();
  float abv = red[0]; int abi = redi[0];
#pragma unroll
  for (int i = 1; i < 16; i++) {
    float ov = red[i]; int oi = redi[i];
    if (ov > abv || (ov == abv && oi < abi)) { abv = ov; abi = oi; }
  }
  float g = gates[k];
#pragma unroll
  for (int j = 0; j < 4; j++) {
    int e = t + j * 1024;
    float egv = eg[j];
    if (EGS < 1.f && e == abi) egv = 1.f;
    out_eg[(size_t)k * EE + e] = egv;
    float eff = (g > 0.5f) ? egv : 1.f;
    egscaled[k * EE + e] = g * eff;
  }
}

// ---------- dispatch 5: Hp row compose + write + adjacency rowscan, block per (n,k) ----------
__global__ void k_hprow(const unsigned* __restrict__ emask,
                        const int* __restrict__ ncnt, const unsigned short* __restrict__ nelist,
                        const float* __restrict__ egs, const float* __restrict__ scal,
                        const float* __restrict__ xhat, const float* __restrict__ xnorm,
                        float* __restrict__ out, float* __restrict__ z) {
  __shared__ float row[EE];
  __shared__ unsigned short elds[MAXNE];
  __shared__ unsigned wpart[4][64];
  __shared__ unsigned short list[2048];
  __shared__ int cnt_s;
  __shared__ float sred[4];
  int k = blockIdx.y, n = blockIdx.x, t = threadIdx.x;
  int ec = ncnt[k * NN + n]; if (ec > MAXNE) ec = MAXNE;
  if (t < ec) elds[t] = nelist[((size_t)(k * NN + n)) * MAXNE + t];
  float4* row4 = (float4*)row;
  float4 z4 = {0.f, 0.f, 0.f, 0.f};
#pragma unroll
  for (int i = 0; i < 4; i++) row4[t + i * 256] = z4;
  if (t == 0) cnt_s = 0;
  __syncthreads();
  if (t < ec) {
    int e = elds[t];
    row[e] = egs[k * EE + e];
  }
  __syncthreads();
  float4* o4 = (float4*)(out + ((size_t)(k * NN + n)) * EE);
#pragma unroll
  for (int i = 0; i < 4; i++) o4[t + i * 256] = row4[t + i * 256];
  // ---- rowscan part ----
  float g = scal[12 + k];
  if (g <= 0.f) { if (t == 0) z[k * NN + n] = 0.f; return; }
  int lane = t & 63, wv = t >> 6;
  unsigned acc = 0;
  for (int it = wv; it < ec; it += 4) {
    int e = (int)elds[it];
    if (row[e] > 0.f) acc |= emask[((size_t)(k * EE) + e) * 64 + lane];
  }
  wpart[wv][lane] = acc;
  __syncthreads();
  if (t < 64) {
    unsigned w = wpart[0][t] | wpart[1][t] | wpart[2][t] | wpart[3][t];
    if (t == (n >> 5)) w &= ~(1u << (n & 31));
    int c = __popc(w);
    if (c > 0) {
      int base = atomicAdd(&cnt_s, c);
      while (w) {
        int b = __builtin_ctz(w); w &= w - 1;
        list[base++] = (unsigned short)((t << 5) + b);
      }
    }
  }
  __syncthreads();
  int cnt = cnt_s;
  if (cnt == 0) { if (t == 0) z[k * NN + n] = 0.f; return; }
  int fc = lane & 31, hh = lane >> 5;
  float4 xn4 = ((const float4*)xhat)[(size_t)n * 32 + fc];
  float a = 0.f;
  for (int it = wv * 2 + hh; it < cnt; it += 8) {
    int m = (int)list[it];
    float4 xm = ((const float4*)xhat)[(size_t)m * 32 + fc];
    a += xn4.x * xm.x + xn4.y * xm.y + xn4.z * xm.z + xn4.w * xm.w;
  }
  for (int o = 32; o > 0; o >>= 1) a += __shfl_xor(a, o, 64);
  if (lane == 0) sred[wv] = a;
  __syncthreads();
  if (t == 0) {
    float s = sred[0] + sred[1] + sred[2] + sred[3];
    z[k * NN + n] = (s / (float)cnt) * xnorm[n];
  }
}

// ---------- dispatch 6: npi = softmax(z) per k ----------
__global__ void k_npi(const float* __restrict__ z, float* __restrict__ out_npi) {
  __shared__ float red[4];
  int k = blockIdx.x, t = threadIdx.x;
  float v[8]; float m = -1e30f;
#pragma unroll
  for (int j = 0; j < 8; j++) { v[j] = z[k * NN + t + j * 256]; m = fmaxf(m, v[j]); }
  for (int o = 32; o > 0; o >>= 1) m = fmaxf(m, __shfl_xor(m, o, 64));
  if ((t & 63) == 0) red[t >> 6] = m;
  __syncthreads();
  m = fmaxf(fmaxf(red[0], red[1]), fmaxf(red[2], red[3]));
  __syncthreads();
  float pe[8]; float s = 0.f;
#pragma unroll
  for (int j = 0; j < 8; j++) { pe[j] = expf(v[j] - m); s += pe[j]; }
  for (int o = 32; o > 0; o >>= 1) s += __shfl_xor(s, o, 64);
  if ((t & 63) == 0) red[t >> 6] = s;
  __syncthreads();
  s = red[0] + red[1] + red[2] + red[3];
#pragma unroll
  for (int j = 0; j < 8; j++) out_npi[k * NN + t + j * 256] = pe[j] / s;
}

extern "C" void kernel_launch(void* const* d_in, const int* in_sizes, int n_in,
                              void* d_out, int out_size, void* d_ws, size_t ws_size,
                              hipStream_t stream) {
  const float* H     = (const float*)d_in[0];
  const float* X     = (const float*)d_in[1];
  const int*   epoch = (const int*)d_in[2];
  const float* w1    = (const float*)d_in[3];
  const float* b1    = (const float*)d_in[4];
  const float* w2    = (const float*)d_in[5];
  const float* b2    = (const float*)d_in[6];
  const float* compW = (const float*)d_in[7];
  const float* aw1   = (const float*)d_in[8];
  const float* ab1   = (const float*)d_in[9];
  const float* aw2   = (const float*)d_in[10];
  const float* ab2   = (const float*)d_in[11];

  char* ws = (char*)d_ws;
  float* xhat  = (float*)(ws + OFF_XHAT);
  float* xnorm = (float*)(ws + OFF_XNORM);
  float* scal  = (float*)(ws + OFF_SCAL);
  int*   ncnt  = (int*)(ws + OFF_NCNT);
  unsigned* emask = (unsigned*)(ws + OFF_EMASK);
  unsigned short* nelist = (unsigned short*)(ws + OFF_NELIST);
  float* impE  = (float*)(ws + OFF_IMPE);
  float* egs   = (float*)(ws + OFF_EGS);
  float* zbuf  = (float*)(ws + OFF_Z);

  float* out       = (float*)d_out;
  float* out_gates = out + (size_t)KCOMP * NN * EE;
  float* out_eg    = out_gates + KCOMP;
  float* out_npi   = out_eg + (size_t)KCOMP * EE;

  k_scanx<<<384, 1024, 0, stream>>>((const float4*)H, emask, X, xhat, xnorm, scal);
  k_mlpf<<<dim3(144, KCOMP), 256, 0, stream>>>(X, w1, b1, w2, b2, aw1, ab1, aw2, ab2,
                                               (const float4*)compW, scal);
  k_nelc<<<dim3(189, KCOMP), 256, 0, stream>>>(emask, ncnt, nelist, xhat, impE);
  k_edgegate<<<KCOMP, 1024, 0, stream>>>(impE, scal, epoch, out_gates, egs, out_eg);
  k_hprow<<<dim3(NN, KCOMP), 256, 0, stream>>>(emask, ncnt, nelist, egs, scal, xhat, xnorm,
                                               out, zbuf);
  k_npi<<<KCOMP, 256, 0, stream>>>(zbuf, out_npi);
}

// Round 8
// 367.140 us; speedup vs baseline: 1.5693x; 1.0184x over previous
//
#include <hip/hip_runtime.h>
#include <math.h>

#define KCOMP 4
#define NN 2048
#define EE 4096
#define DD 128
#define MAXNE 96
#define MAXSE 500
#define BETA_C 0.6f
#define EPS_G 0.01f
#define LAM_S 0.05f
#define TC0_C 0.3f
#define TCMAX_C 0.7f
#define COS_EPS_C 1e-8f

// ---- workspace layout (bytes) ----
static const size_t OFF_XHAT   = 0;          // N*D f32 = 1 MB
static const size_t OFF_XNORM  = 1048576;    // N f32 = 8 KB
static const size_t OFF_SCAL   = 1056768;    // 256 B (zeroed by k_scanx block 256)
static const size_t OFF_NCNT   = 1057024;    // K*N i32 = 32 KB
static const size_t OFF_EMASK  = 1089792;    // K*E*64 u32 = 4 MB (fully written)
static const size_t OFF_NELIST = 5284096;    // K*N*96 u16 = 1.5 MB
static const size_t OFF_IMPE   = 6856960;    // K*512 f32 = 8 KB
static const size_t OFF_EGS    = 6865152;    // K*E f32 = 64 KB
static const size_t OFF_Z      = 6930688;    // K*N f32 = 32 KB

// ---------- dispatch 1: H scan (line-aligned both ways) + xhat + scal zero ----------
// blocks [0,256): scan. block = (k, ch_super in [0,4), e4_super in [0,16)).
//   1024 threads = 16 chi x 64 e4i. Thread owns (ch = ch_super*16+chi) x (e4 = e4_super*64+e4i):
//   reads 32 rows (1 KB contiguous per wave-instr), builds 4 edges x 1 word,
//   stages in LDS, writes emask in full 64 B line units (16 words/edge per block).
// blocks [256,384): xhat, 16 nodes per block (wave per node).
__global__ __launch_bounds__(1024) void k_scanx(
    const float4* __restrict__ H4, unsigned* __restrict__ emask,
    const float* __restrict__ X, float* __restrict__ xhat, float* __restrict__ xnorm,
    float* __restrict__ scal) {
  int b = blockIdx.x, t = threadIdx.x;
  if (b < 256) {
    __shared__ unsigned lds[256 * 17];       // [e_local][word] stride 17 (pad)
    int k = b >> 6;
    int rem = b & 63;
    int ch_super = rem >> 4;
    int e4_super = rem & 15;
    int chi = t >> 6;                        // [0,16)
    int e4i = t & 63;                        // [0,64)
    int ch = ch_super * 16 + chi;
    int e4 = e4_super * 64 + e4i;
    int n0 = ch * 32;
    const float4* p = H4 + ((size_t)(k * NN + n0)) * (EE / 4) + e4;
    unsigned w0 = 0, w1 = 0, w2 = 0, w3 = 0;
    for (int rb = 0; rb < 32; rb += 8) {
      float4 v[8];
#pragma unroll
      for (int u = 0; u < 8; ++u) v[u] = p[(size_t)(rb + u) * (EE / 4)];
#pragma unroll
      for (int u = 0; u < 8; ++u) {
        unsigned bit = 1u << (rb + u);
        w0 |= (v[u].x > 0.f) ? bit : 0u;
        w1 |= (v[u].y > 0.f) ? bit : 0u;
        w2 |= (v[u].z > 0.f) ? bit : 0u;
        w3 |= (v[u].w > 0.f) ? bit : 0u;
      }
    }
    int el = e4i * 4;
    lds[(el + 0) * 17 + chi] = w0;
    lds[(el + 1) * 17 + chi] = w1;
    lds[(el + 2) * 17 + chi] = w2;
    lds[(el + 3) * 17 + chi] = w3;
    __syncthreads();
    // write out: 4 iters x 1024 threads x 4 B = 16 KB; 16 lanes = 64 B line per edge
    int e_base = e4_super * 256;
    int wi = t & 15;
    int eo = t >> 4;                         // [0,64)
#pragma unroll
    for (int it = 0; it < 4; ++it) {
      int e_local = it * 64 + eo;
      emask[((size_t)(k * EE) + e_base + e_local) * 64 + ch_super * 16 + wi] =
          lds[e_local * 17 + wi];
    }
  } else {
    if (b == 256 && t < 64) scal[t] = 0.f;
    int node = (b - 256) * 16 + (t >> 6);
    int lane = t & 63;
    float2 v = ((const float2*)X)[(size_t)node * 64 + lane];
    float ss = v.x * v.x + v.y * v.y;
    for (int o = 32; o > 0; o >>= 1) ss += __shfl_xor(ss, o, 64);
    float nrm = sqrtf(ss);
    float den = fmaxf(nrm, COS_EPS_C);
    if (lane == 0) xnorm[node] = nrm;
    float2 o2; o2.x = v.x / den; o2.y = v.y / den;
    ((float2*)xhat)[(size_t)node * 64 + lane] = o2;
  }
}

// ---------- dispatch 2: fused MLP chain (x<128) + frobenius (x>=128) ----------
__global__ void k_mlpf(const float* __restrict__ X,
                       const float* __restrict__ w1, const float* __restrict__ b1,
                       const float* __restrict__ w2, const float* __restrict__ b2,
                       const float* __restrict__ aw1, const float* __restrict__ ab1,
                       const float* __restrict__ aw2, const float* __restrict__ ab2,
                       const float4* __restrict__ compW4, float* __restrict__ scal) {
  __shared__ float Xs[16 * 128];
  __shared__ float H1s[16 * 128];
  __shared__ float XKs[16 * 128];
  __shared__ float A1s[16 * 64];
  __shared__ float red[16];
  int t = threadIdx.x;
  int k = blockIdx.y;
  if (blockIdx.x >= 128) {   // frobenius^2 partial: 16 blocks x 256 threads x float4
    float4 v = compW4[(size_t)k * 4096 + (blockIdx.x - 128) * 256 + t];
    float s = v.x * v.x + v.y * v.y + v.z * v.z + v.w * v.w;
    for (int o = 32; o > 0; o >>= 1) s += __shfl_xor(s, o, 64);
    if ((t & 63) == 0) red[t >> 6] = s;
    __syncthreads();
    if (t == 0) atomicAdd(&scal[8 + k], red[0] + red[1] + red[2] + red[3]);
    return;
  }
  int n0 = blockIdx.x * 16;
  for (int i = t; i < 16 * 128; i += 256) Xs[i] = X[(size_t)n0 * 128 + i];
  __syncthreads();

  int h = t & 127, g = t >> 7;
  const float* W1 = w1 + (size_t)k * 128 * 128;
  float acc[8];
  float bb = b1[k * 128 + h];
#pragma unroll
  for (int i = 0; i < 8; i++) acc[i] = bb;
  for (int d = 0; d < 128; ++d) {
    float w = W1[d * 128 + h];
#pragma unroll
    for (int i = 0; i < 8; i++) acc[i] = fmaf(Xs[(g * 8 + i) * 128 + d], w, acc[i]);
  }
#pragma unroll
  for (int i = 0; i < 8; i++) H1s[(g * 8 + i) * 128 + h] = fmaxf(acc[i], 0.f);
  __syncthreads();

  const float* W2 = w2 + (size_t)k * 128 * 128;
  bb = b2[k * 128 + h];
#pragma unroll
  for (int i = 0; i < 8; i++) acc[i] = bb;
  for (int d = 0; d < 128; ++d) {
    float w = W2[d * 128 + h];
#pragma unroll
    for (int i = 0; i < 8; i++) acc[i] = fmaf(H1s[(g * 8 + i) * 128 + d], w, acc[i]);
  }
  float fpart = 0.f;
#pragma unroll
  for (int i = 0; i < 8; i++) { XKs[(g * 8 + i) * 128 + h] = acc[i]; fpart = fmaf(acc[i], acc[i], fpart); }
  __syncthreads();

  int h2 = t & 63, g4 = t >> 6;
  const float* AW1 = aw1 + (size_t)k * 128 * 64;
  float a4[4];
  float ab = ab1[k * 64 + h2];
#pragma unroll
  for (int i = 0; i < 4; i++) a4[i] = ab;
  for (int d = 0; d < 128; ++d) {
    float w = AW1[d * 64 + h2];
#pragma unroll
    for (int i = 0; i < 4; i++) a4[i] = fmaf(XKs[(g4 * 4 + i) * 128 + d], w, a4[i]);
  }
#pragma unroll
  for (int i = 0; i < 4; i++) A1s[(g4 * 4 + i) * 64 + h2] = fmaxf(a4[i], 0.f);
  __syncthreads();

  float attsum = 0.f;
  if (t < 16) {
    const float* AW2 = aw2 + (size_t)k * 64;
    float a = ab2[k];
    for (int d = 0; d < 64; ++d) a = fmaf(A1s[t * 64 + d], AW2[d], a);
    attsum = 1.f / (1.f + expf(-a));
  }
  for (int o = 32; o > 0; o >>= 1) {
    fpart  += __shfl_xor(fpart, o, 64);
    attsum += __shfl_xor(attsum, o, 64);
  }
  int wv = t >> 6, ln = t & 63;
  if (ln == 0) { red[wv] = fpart; red[8 + wv] = attsum; }
  __syncthreads();
  if (t == 0) {
    float fs = red[0] + red[1] + red[2] + red[3];
    float as = red[8] + red[9] + red[10] + red[11];
    atomicAdd(&scal[0 + k], fs);
    atomicAdd(&scal[4 + k], as);
  }
}

// ---------- dispatch 3: nelist transpose (x<64) + cosine importance (x>=64) ----------
__global__ void k_nelc(const unsigned* __restrict__ emask, int* __restrict__ ncnt,
                       unsigned short* __restrict__ nelist, const float* __restrict__ xhat,
                       float* __restrict__ impE) {
  int k = blockIdx.y, t = threadIdx.x;
  if (blockIdx.x < 64) {
    __shared__ unsigned short lst[32][MAXNE];
    __shared__ int lcnt[32];
    int w = blockIdx.x;
    if (t < 32) lcnt[t] = 0;
    __syncthreads();
    for (int e = t; e < EE; e += 256) {
      unsigned wd = emask[((size_t)(k * EE) + e) * 64 + w];
      while (wd) {
        int b = __builtin_ctz(wd); wd &= wd - 1;
        int slot = atomicAdd(&lcnt[b], 1);
        if (slot < MAXNE) lst[b][slot] = (unsigned short)e;
      }
    }
    __syncthreads();
    if (t < 32) ncnt[k * NN + w * 32 + t] = lcnt[t];
    for (int i = t; i < 32 * MAXNE; i += 256) {
      int b = i / MAXNE, s = i - b * MAXNE;
      int c = lcnt[b]; if (c > MAXNE) c = MAXNE;
      if (s < c) nelist[((size_t)(k * NN + w * 32 + b)) * MAXNE + s] = lst[b][s];
    }
    return;
  }
  // cosimp: wave per edge, e in [0,500)
  int e = (blockIdx.x - 64) * 4 + (t >> 6);
  int lane = t & 63;
  unsigned w = emask[((size_t)(k * EE) + e) * 64 + lane];
  int pc = __popc(w);
  for (int o = 32; o > 0; o >>= 1) pc += __shfl_xor(pc, o, 64);
  float impv = 0.1f;
  if (pc >= 2) {   // H binary -> A_ij = 1; i,j = two lowest member indices
    unsigned l1 = w ? (unsigned)((lane << 5) + __builtin_ctz(w)) : 0xffffffffu;
    unsigned wr = w & (w - 1);
    unsigned l2 = wr ? (unsigned)((lane << 5) + __builtin_ctz(wr)) : 0xffffffffu;
    unsigned g1 = l1;
    for (int o = 32; o > 0; o >>= 1) {
      unsigned x = (unsigned)__shfl_xor((int)g1, o, 64);
      g1 = g1 < x ? g1 : x;
    }
    unsigned cand = (l1 == g1) ? l2 : l1;
    unsigned g2 = cand;
    for (int o = 32; o > 0; o >>= 1) {
      unsigned x = (unsigned)__shfl_xor((int)g2, o, 64);
      g2 = g2 < x ? g2 : x;
    }
    float2 xi = ((const float2*)xhat)[(size_t)g1 * 64 + lane];
    float2 xj = ((const float2*)xhat)[(size_t)g2 * 64 + lane];
    float d = xi.x * xj.x + xi.y * xj.y;
    for (int o = 32; o > 0; o >>= 1) d += __shfl_xor(d, o, 64);
    impv = d;
  }
  if (lane == 0) impE[k * 512 + e] = impv;
}

// ---------- dispatch 4: edge softmax + gating; component gates computed in-block ----------
__device__ __forceinline__ float blockReduceSum16(float v, float* red, int t) {
  for (int o = 32; o > 0; o >>= 1) v += __shfl_xor(v, o, 64);
  __syncthreads();
  if ((t & 63) == 0) red[t >> 6] = v;
  __syncthreads();
  float s = red[0];
#pragma unroll
  for (int i = 1; i < 16; i++) s += red[i];
  return s;
}

__global__ void k_edgegate(const float* __restrict__ impE, float* __restrict__ scal,
                           const int* __restrict__ epoch, float* __restrict__ out_gates,
                           float* __restrict__ egscaled, float* __restrict__ out_eg) {
  __shared__ float red[16];
  __shared__ int redi[16];
  int k = blockIdx.x;
  int t = threadIdx.x;
  // --- component gates (every thread recomputes; deterministic identical) ---
  float gates[KCOMP];
  float tc;
  {
    float imp[KCOMP];
    for (int kk = 0; kk < KCOMP; kk++) {
      float featn = sqrtf(scal[0 + kk]);
      float satt  = scal[4 + kk] / (float)NN;
      float frob  = sqrtf(scal[8 + kk]);
      imp[kk] = BETA_C * frob * featn + (1.f - BETA_C) * satt;
    }
    float mx = imp[0];
    for (int kk = 1; kk < KCOMP; kk++) mx = fmaxf(mx, imp[kk]);
    float ex[KCOMP], ssum = 0.f;
    for (int kk = 0; kk < KCOMP; kk++) { ex[kk] = expf(imp[kk] - mx); ssum += ex[kk]; }
    tc = TC0_C + (1.f - expf(-LAM_S * (float)epoch[0])) * (TCMAX_C - TC0_C);
    for (int kk = 0; kk < KCOMP; kk++) {
      float pi = ex[kk] / ssum;
      gates[kk] = fminf(fmaxf((pi - tc) / EPS_G + 0.5f, 0.f), 1.f);
    }
    int am = 0; float bv2 = gates[0];
    for (int kk = 1; kk < KCOMP; kk++) if (gates[kk] > bv2) { bv2 = gates[kk]; am = kk; }
    gates[am] = fmaxf(gates[am], 1.f);
  }
  if (t == 0) {
    scal[12 + k] = gates[k];
    if (k == 0) for (int kk = 0; kk < KCOMP; kk++) out_gates[kk] = gates[kk];
  }
  // --- edge softmax ---
  float imp[4];
#pragma unroll
  for (int j = 0; j < 4; j++) {
    int e = t + j * 1024;
    imp[j] = (e < MAXSE) ? impE[k * 512 + e] : 0.f;
  }
  float m = fmaxf(fmaxf(imp[0], imp[1]), fmaxf(imp[2], imp[3]));
  for (int o = 32; o > 0; o >>= 1) m = fmaxf(m, __shfl_xor(m, o, 64));
  __syncthreads();
  if ((t & 63) == 0) red[t >> 6] = m;
  __syncthreads();
  m = red[0];
#pragma unroll
  for (int i = 1; i < 16; i++) m = fmaxf(m, red[i]);
  float p[4], psum = 0.f;
#pragma unroll
  for (int j = 0; j < 4; j++) { p[j] = expf(imp[j] - m); psum += p[j]; }
  float S = blockReduceSum16(psum, red, t);
  float pi[4], tot = 0.f;
#pragma unroll
  for (int j = 0; j < 4; j++) { pi[j] = p[j] / S; tot += pi[j]; }
  float T = blockReduceSum16(tot, red, t);
  float mean = T / (float)EE;
  float devs = 0.f;
#pragma unroll
  for (int j = 0; j < 4; j++) { float d = pi[j] - mean; devs = fmaf(d, d, devs); }
  float V = blockReduceSum16(devs, red, t);
  float stdv = sqrtf(V / (float)(EE - 1));
  float theta = fminf(tc, mean + stdv);
  float eg[4], egsum = 0.f;
#pragma unroll
  for (int j = 0; j < 4; j++) {
    eg[j] = fminf(fmaxf((pi[j] - theta) / EPS_G + 0.5f, 0.f), 1.f);
    egsum += eg[j];
  }
  float EGS = blockReduceSum16(egsum, red, t);
  float bv = -1e30f; int bi = 0x7fffffff;
#pragma unroll
  for (int j = 0; j < 4; j++) if (pi[j] > bv) { bv = pi[j]; bi = t + j * 1024; }
  for (int o = 32; o > 0; o >>= 1) {
    float ov = __shfl_xor(bv, o, 64); int oi = __shfl_xor(bi, o, 64);
    if (ov > bv || (ov == bv && oi < bi)) { bv = ov; bi = oi; }
  }
  __syncthreads();
  if ((t & 63) == 0) { red[t >> 6] = bv; redi[t >> 6] = bi; }
  __syncthreads();
  float abv = red[0]; int abi = redi[0];
#pragma unroll
  for (int i = 1; i < 16; i++) {
    float ov = red[i]; int oi = redi[i];
    if (ov > abv || (ov == abv && oi < abi)) { abv = ov; abi = oi; }
  }
  float g = gates[k];
#pragma unroll
  for (int j = 0; j < 4; j++) {
    int e = t + j * 1024;
    float egv = eg[j];
    if (EGS < 1.f && e == abi) egv = 1.f;
    out_eg[(size_t)k * EE + e] = egv;
    float eff = (g > 0.5f) ? egv : 1.f;
    egscaled[k * EE + e] = g * eff;
  }
}

// ---------- dispatch 5: Hp row compose + write + adjacency rowscan, block per (n,k) ----------
__global__ void k_hprow(const unsigned* __restrict__ emask,
                        const int* __restrict__ ncnt, const unsigned short* __restrict__ nelist,
                        const float* __restrict__ egs, const float* __restrict__ scal,
                        const float* __restrict__ xhat, const float* __restrict__ xnorm,
                        float* __restrict__ out, float* __restrict__ z) {
  __shared__ float row[EE];
  __shared__ unsigned short elds[MAXNE];
  __shared__ unsigned wpart[4][64];
  __shared__ unsigned short list[2048];
  __shared__ int cnt_s;
  __shared__ float sred[4];
  int k = blockIdx.y, n = blockIdx.x, t = threadIdx.x;
  int ec = ncnt[k * NN + n]; if (ec > MAXNE) ec = MAXNE;
  if (t < ec) elds[t] = nelist[((size_t)(k * NN + n)) * MAXNE + t];
  float4* row4 = (float4*)row;
  float4 z4 = {0.f, 0.f, 0.f, 0.f};
#pragma unroll
  for (int i = 0; i < 4; i++) row4[t + i * 256] = z4;
  if (t == 0) cnt_s = 0;
  __syncthreads();
  if (t < ec) {
    int e = elds[t];
    row[e] = egs[k * EE + e];
  }
  __syncthreads();
  float4* o4 = (float4*)(out + ((size_t)(k * NN + n)) * EE);
#pragma unroll
  for (int i = 0; i < 4; i++) o4[t + i * 256] = row4[t + i * 256];
  // ---- rowscan part ----
  float g = scal[12 + k];
  if (g <= 0.f) { if (t == 0) z[k * NN + n] = 0.f; return; }
  int lane = t & 63, wv = t >> 6;
  unsigned acc = 0;
  for (int it = wv; it < ec; it += 4) {
    int e = (int)elds[it];
    if (row[e] > 0.f) acc |= emask[((size_t)(k * EE) + e) * 64 + lane];
  }
  wpart[wv][lane] = acc;
  __syncthreads();
  if (t < 64) {
    unsigned w = wpart[0][t] | wpart[1][t] | wpart[2][t] | wpart[3][t];
    if (t == (n >> 5)) w &= ~(1u << (n & 31));
    int c = __popc(w);
    if (c > 0) {
      int base = atomicAdd(&cnt_s, c);
      while (w) {
        int b = __builtin_ctz(w); w &= w - 1;
        list[base++] = (unsigned short)((t << 5) + b);
      }
    }
  }
  __syncthreads();
  int cnt = cnt_s;
  if (cnt == 0) { if (t == 0) z[k * NN + n] = 0.f; return; }
  int fc = lane & 31, hh = lane >> 5;
  float4 xn4 = ((const float4*)xhat)[(size_t)n * 32 + fc];
  float a = 0.f;
  for (int it = wv * 2 + hh; it < cnt; it += 8) {
    int m = (int)list[it];
    float4 xm = ((const float4*)xhat)[(size_t)m * 32 + fc];
    a += xn4.x * xm.x + xn4.y * xm.y + xn4.z * xm.z + xn4.w * xm.w;
  }
  for (int o = 32; o > 0; o >>= 1) a += __shfl_xor(a, o, 64);
  if (lane == 0) sred[wv] = a;
  __syncthreads();
  if (t == 0) {
    float s = sred[0] + sred[1] + sred[2] + sred[3];
    z[k * NN + n] = (s / (float)cnt) * xnorm[n];
  }
}

// ---------- dispatch 6: npi = softmax(z) per k ----------
__global__ void k_npi(const float* __restrict__ z, float* __restrict__ out_npi) {
  __shared__ float red[4];
  int k = blockIdx.x, t = threadIdx.x;
  float v[8]; float m = -1e30f;
#pragma unroll
  for (int j = 0; j < 8; j++) { v[j] = z[k * NN + t + j * 256]; m = fmaxf(m, v[j]); }
  for (int o = 32; o > 0; o >>= 1) m = fmaxf(m, __shfl_xor(m, o, 64));
  if ((t & 63) == 0) red[t >> 6] = m;
  __syncthreads();
  m = fmaxf(fmaxf(red[0], red[1]), fmaxf(red[2], red[3]));
  __syncthreads();
  float pe[8]; float s = 0.f;
#pragma unroll
  for (int j = 0; j < 8; j++) { pe[j] = expf(v[j] - m); s += pe[j]; }
  for (int o = 32; o > 0; o >>= 1) s += __shfl_xor(s, o, 64);
  if ((t & 63) == 0) red[t >> 6] = s;
  __syncthreads();
  s = red[0] + red[1] + red[2] + red[3];
#pragma unroll
  for (int j = 0; j < 8; j++) out_npi[k * NN + t + j * 256] = pe[j] / s;
}

extern "C" void kernel_launch(void* const* d_in, const int* in_sizes, int n_in,
                              void* d_out, int out_size, void* d_ws, size_t ws_size,
                              hipStream_t stream) {
  const float* H     = (const float*)d_in[0];
  const float* X     = (const float*)d_in[1];
  const int*   epoch = (const int*)d_in[2];
  const float* w1    = (const float*)d_in[3];
  const float* b1    = (const float*)d_in[4];
  const float* w2    = (const float*)d_in[5];
  const float* b2    = (const float*)d_in[6];
  const float* compW = (const float*)d_in[7];
  const float* aw1   = (const float*)d_in[8];
  const float* ab1   = (const float*)d_in[9];
  const float* aw2   = (const float*)d_in[10];
  const float* ab2   = (const float*)d_in[11];

  char* ws = (char*)d_ws;
  float* xhat  = (float*)(ws + OFF_XHAT);
  float* xnorm = (float*)(ws + OFF_XNORM);
  float* scal  = (float*)(ws + OFF_SCAL);
  int*   ncnt  = (int*)(ws + OFF_NCNT);
  unsigned* emask = (unsigned*)(ws + OFF_EMASK);
  unsigned short* nelist = (unsigned short*)(ws + OFF_NELIST);
  float* impE  = (float*)(ws + OFF_IMPE);
  float* egs   = (float*)(ws + OFF_EGS);
  float* zbuf  = (float*)(ws + OFF_Z);

  float* out       = (float*)d_out;
  float* out_gates = out + (size_t)KCOMP * NN * EE;
  float* out_eg    = out_gates + KCOMP;
  float* out_npi   = out_eg + (size_t)KCOMP * EE;

  k_scanx<<<384, 1024, 0, stream>>>((const float4*)H, emask, X, xhat, xnorm, scal);
  k_mlpf<<<dim3(144, KCOMP), 256, 0, stream>>>(X, w1, b1, w2, b2, aw1, ab1, aw2, ab2,
                                               (const float4*)compW, scal);
  k_nelc<<<dim3(189, KCOMP), 256, 0, stream>>>(emask, ncnt, nelist, xhat, impE);
  k_edgegate<<<KCOMP, 1024, 0, stream>>>(impE, scal, epoch, out_gates, egs, out_eg);
  k_hprow<<<dim3(NN, KCOMP), 256, 0, stream>>>(emask, ncnt, nelist, egs, scal, xhat, xnorm,
                                               out, zbuf);
  k_npi<<<KCOMP, 256, 0, stream>>>(zbuf, out_npi);
}

// Round 9
// 353.076 us; speedup vs baseline: 1.6318x; 1.0398x over previous
//
#include <hip/hip_runtime.h>
#include <math.h>

#define KCOMP 4
#define NN 2048
#define EE 4096
#define DD 128
#define MAXNE 96
#define MAXSE 500
#define BETA_C 0.6f
#define EPS_G 0.01f
#define LAM_S 0.05f
#define TC0_C 0.3f
#define TCMAX_C 0.7f
#define COS_EPS_C 1e-8f

// ---- workspace layout (bytes) ----
static const size_t OFF_XHAT   = 0;          // N*D f32 = 1 MB
static const size_t OFF_XNORM  = 1048576;    // N f32 = 8 KB
static const size_t OFF_SCAL   = 1056768;    // 256 B (zeroed by k_scanx block 256)
static const size_t OFF_NCNT   = 1057024;    // K*N i32 = 32 KB
static const size_t OFF_EMASK  = 1089792;    // K*E*64 u32 = 4 MB (fully written)
static const size_t OFF_NELIST = 5284096;    // K*N*96 u16 = 1.5 MB
static const size_t OFF_IMPE   = 6856960;    // K*512 f32 = 8 KB
static const size_t OFF_EGS    = 6865152;    // K*E f32 = 64 KB
static const size_t OFF_Z      = 6930688;    // K*N f32 = 32 KB

// ---------- dispatch 1: H scan (line-aligned both ways) + xhat + scal zero ----------
__global__ __launch_bounds__(1024) void k_scanx(
    const float4* __restrict__ H4, unsigned* __restrict__ emask,
    const float* __restrict__ X, float* __restrict__ xhat, float* __restrict__ xnorm,
    float* __restrict__ scal) {
  int b = blockIdx.x, t = threadIdx.x;
  if (b < 256) {
    __shared__ unsigned lds[256 * 17];       // [e_local][word] stride 17 (pad)
    int k = b >> 6;
    int rem = b & 63;
    int ch_super = rem >> 4;
    int e4_super = rem & 15;
    int chi = t >> 6;                        // [0,16)
    int e4i = t & 63;                        // [0,64)
    int ch = ch_super * 16 + chi;
    int e4 = e4_super * 64 + e4i;
    int n0 = ch * 32;
    const float4* p = H4 + ((size_t)(k * NN + n0)) * (EE / 4) + e4;
    unsigned w0 = 0, w1 = 0, w2 = 0, w3 = 0;
    for (int rb = 0; rb < 32; rb += 8) {
      float4 v[8];
#pragma unroll
      for (int u = 0; u < 8; ++u) v[u] = p[(size_t)(rb + u) * (EE / 4)];
#pragma unroll
      for (int u = 0; u < 8; ++u) {
        unsigned bit = 1u << (rb + u);
        w0 |= (v[u].x > 0.f) ? bit : 0u;
        w1 |= (v[u].y > 0.f) ? bit : 0u;
        w2 |= (v[u].z > 0.f) ? bit : 0u;
        w3 |= (v[u].w > 0.f) ? bit : 0u;
      }
    }
    int el = e4i * 4;
    lds[(el + 0) * 17 + chi] = w0;
    lds[(el + 1) * 17 + chi] = w1;
    lds[(el + 2) * 17 + chi] = w2;
    lds[(el + 3) * 17 + chi] = w3;
    __syncthreads();
    int e_base = e4_super * 256;
    int wi = t & 15;
    int eo = t >> 4;                         // [0,64)
#pragma unroll
    for (int it = 0; it < 4; ++it) {
      int e_local = it * 64 + eo;
      emask[((size_t)(k * EE) + e_base + e_local) * 64 + ch_super * 16 + wi] =
          lds[e_local * 17 + wi];
    }
  } else {
    if (b == 256 && t < 64) scal[t] = 0.f;
    int node = (b - 256) * 16 + (t >> 6);
    int lane = t & 63;
    float2 v = ((const float2*)X)[(size_t)node * 64 + lane];
    float ss = v.x * v.x + v.y * v.y;
    for (int o = 32; o > 0; o >>= 1) ss += __shfl_xor(ss, o, 64);
    float nrm = sqrtf(ss);
    float den = fmaxf(nrm, COS_EPS_C);
    if (lane == 0) xnorm[node] = nrm;
    float2 o2; o2.x = v.x / den; o2.y = v.y / den;
    ((float2*)xhat)[(size_t)node * 64 + lane] = o2;
  }
}

// ---------- dispatch 2: MLP chain (x<128) + frobenius (x in [128,144)) +
//            nelist transpose (x in [144,208)) + cosine importance (x in [208,333)) ----------
__global__ void k_mlnel(const float* __restrict__ X,
                        const float* __restrict__ w1, const float* __restrict__ b1,
                        const float* __restrict__ w2, const float* __restrict__ b2,
                        const float* __restrict__ aw1, const float* __restrict__ ab1,
                        const float* __restrict__ aw2, const float* __restrict__ ab2,
                        const float4* __restrict__ compW4, float* __restrict__ scal,
                        const unsigned* __restrict__ emask, int* __restrict__ ncnt,
                        unsigned short* __restrict__ nelist, const float* __restrict__ xhat,
                        float* __restrict__ impE) {
  __shared__ char smem[28736];
  int t = threadIdx.x;
  int k = blockIdx.y;
  int bx = blockIdx.x;
  if (bx >= 208) {
    // --- cosimp: wave per edge, e in [0,500) ---
    int e = (bx - 208) * 4 + (t >> 6);
    int lane = t & 63;
    unsigned w = emask[((size_t)(k * EE) + e) * 64 + lane];
    int pc = __popc(w);
    for (int o = 32; o > 0; o >>= 1) pc += __shfl_xor(pc, o, 64);
    float impv = 0.1f;
    if (pc >= 2) {   // H binary -> A_ij = 1; i,j = two lowest member indices
      unsigned l1 = w ? (unsigned)((lane << 5) + __builtin_ctz(w)) : 0xffffffffu;
      unsigned wr = w & (w - 1);
      unsigned l2 = wr ? (unsigned)((lane << 5) + __builtin_ctz(wr)) : 0xffffffffu;
      unsigned g1 = l1;
      for (int o = 32; o > 0; o >>= 1) {
        unsigned x = (unsigned)__shfl_xor((int)g1, o, 64);
        g1 = g1 < x ? g1 : x;
      }
      unsigned cand = (l1 == g1) ? l2 : l1;
      unsigned g2 = cand;
      for (int o = 32; o > 0; o >>= 1) {
        unsigned x = (unsigned)__shfl_xor((int)g2, o, 64);
        g2 = g2 < x ? g2 : x;
      }
      float2 xi = ((const float2*)xhat)[(size_t)g1 * 64 + lane];
      float2 xj = ((const float2*)xhat)[(size_t)g2 * 64 + lane];
      float d = xi.x * xj.x + xi.y * xj.y;
      for (int o = 32; o > 0; o >>= 1) d += __shfl_xor(d, o, 64);
      impv = d;
    }
    if (lane == 0) impE[k * 512 + e] = impv;
    return;
  }
  if (bx >= 144) {
    // --- nelist transpose; word w = bx-144 covers 32 nodes ---
    unsigned short* lst = (unsigned short*)smem;           // [32][MAXNE]
    int* lcnt = (int*)(smem + 32 * MAXNE * 2);
    int w = bx - 144;
    if (t < 32) lcnt[t] = 0;
    __syncthreads();
    for (int e = t; e < EE; e += 256) {
      unsigned wd = emask[((size_t)(k * EE) + e) * 64 + w];
      while (wd) {
        int b = __builtin_ctz(wd); wd &= wd - 1;
        int slot = atomicAdd(&lcnt[b], 1);
        if (slot < MAXNE) lst[b * MAXNE + slot] = (unsigned short)e;
      }
    }
    __syncthreads();
    if (t < 32) ncnt[k * NN + w * 32 + t] = lcnt[t];
    for (int i = t; i < 32 * MAXNE; i += 256) {
      int b = i / MAXNE, s = i - b * MAXNE;
      int c = lcnt[b]; if (c > MAXNE) c = MAXNE;
      if (s < c) nelist[((size_t)(k * NN + w * 32 + b)) * MAXNE + s] = lst[b * MAXNE + s];
    }
    return;
  }
  float* Xs  = (float*)smem;            // 16*128
  float* H1s = Xs + 2048;               // 16*128
  float* XKs = H1s + 2048;              // 16*128
  float* A1s = XKs + 2048;              // 16*64
  float* red = A1s + 1024;              // 16
  if (bx >= 128) {   // frobenius^2 partial: 16 blocks x 256 threads x float4
    float4 v = compW4[(size_t)k * 4096 + (bx - 128) * 256 + t];
    float s = v.x * v.x + v.y * v.y + v.z * v.z + v.w * v.w;
    for (int o = 32; o > 0; o >>= 1) s += __shfl_xor(s, o, 64);
    if ((t & 63) == 0) red[t >> 6] = s;
    __syncthreads();
    if (t == 0) atomicAdd(&scal[8 + k], red[0] + red[1] + red[2] + red[3]);
    return;
  }
  int n0 = bx * 16;
  for (int i = t; i < 16 * 128; i += 256) Xs[i] = X[(size_t)n0 * 128 + i];
  __syncthreads();

  int h = t & 127, g = t >> 7;
  const float* W1 = w1 + (size_t)k * 128 * 128;
  float acc[8];
  float bb = b1[k * 128 + h];
#pragma unroll
  for (int i = 0; i < 8; i++) acc[i] = bb;
  for (int d = 0; d < 128; ++d) {
    float w = W1[d * 128 + h];
#pragma unroll
    for (int i = 0; i < 8; i++) acc[i] = fmaf(Xs[(g * 8 + i) * 128 + d], w, acc[i]);
  }
#pragma unroll
  for (int i = 0; i < 8; i++) H1s[(g * 8 + i) * 128 + h] = fmaxf(acc[i], 0.f);
  __syncthreads();

  const float* W2 = w2 + (size_t)k * 128 * 128;
  bb = b2[k * 128 + h];
#pragma unroll
  for (int i = 0; i < 8; i++) acc[i] = bb;
  for (int d = 0; d < 128; ++d) {
    float w = W2[d * 128 + h];
#pragma unroll
    for (int i = 0; i < 8; i++) acc[i] = fmaf(H1s[(g * 8 + i) * 128 + d], w, acc[i]);
  }
  float fpart = 0.f;
#pragma unroll
  for (int i = 0; i < 8; i++) { XKs[(g * 8 + i) * 128 + h] = acc[i]; fpart = fmaf(acc[i], acc[i], fpart); }
  __syncthreads();

  int h2 = t & 63, g4 = t >> 6;
  const float* AW1 = aw1 + (size_t)k * 128 * 64;
  float a4[4];
  float ab = ab1[k * 64 + h2];
#pragma unroll
  for (int i = 0; i < 4; i++) a4[i] = ab;
  for (int d = 0; d < 128; ++d) {
    float w = AW1[d * 64 + h2];
#pragma unroll
    for (int i = 0; i < 4; i++) a4[i] = fmaf(XKs[(g4 * 4 + i) * 128 + d], w, a4[i]);
  }
#pragma unroll
  for (int i = 0; i < 4; i++) A1s[(g4 * 4 + i) * 64 + h2] = fmaxf(a4[i], 0.f);
  __syncthreads();

  float attsum = 0.f;
  if (t < 16) {
    const float* AW2 = aw2 + (size_t)k * 64;
    float a = ab2[k];
    for (int d = 0; d < 64; ++d) a = fmaf(A1s[t * 64 + d], AW2[d], a);
    attsum = 1.f / (1.f + expf(-a));
  }
  for (int o = 32; o > 0; o >>= 1) {
    fpart  += __shfl_xor(fpart, o, 64);
    attsum += __shfl_xor(attsum, o, 64);
  }
  int wv = t >> 6, ln = t & 63;
  if (ln == 0) { red[wv] = fpart; red[8 + wv] = attsum; }
  __syncthreads();
  if (t == 0) {
    float fs = red[0] + red[1] + red[2] + red[3];
    float as = red[8] + red[9] + red[10] + red[11];
    atomicAdd(&scal[0 + k], fs);
    atomicAdd(&scal[4 + k], as);
  }
}

// ---------- dispatch 3: edge softmax + gating; component gates computed in-block ----------
__device__ __forceinline__ float blockReduceSum16(float v, float* red, int t) {
  for (int o = 32; o > 0; o >>= 1) v += __shfl_xor(v, o, 64);
  __syncthreads();
  if ((t & 63) == 0) red[t >> 6] = v;
  __syncthreads();
  float s = red[0];
#pragma unroll
  for (int i = 1; i < 16; i++) s += red[i];
  return s;
}

__global__ void k_edgegate(const float* __restrict__ impE, float* __restrict__ scal,
                           const int* __restrict__ epoch, float* __restrict__ out_gates,
                           float* __restrict__ egscaled, float* __restrict__ out_eg) {
  __shared__ float red[16];
  __shared__ int redi[16];
  int k = blockIdx.x;
  int t = threadIdx.x;
  float gates[KCOMP];
  float tc;
  {
    float imp[KCOMP];
    for (int kk = 0; kk < KCOMP; kk++) {
      float featn = sqrtf(scal[0 + kk]);
      float satt  = scal[4 + kk] / (float)NN;
      float frob  = sqrtf(scal[8 + kk]);
      imp[kk] = BETA_C * frob * featn + (1.f - BETA_C) * satt;
    }
    float mx = imp[0];
    for (int kk = 1; kk < KCOMP; kk++) mx = fmaxf(mx, imp[kk]);
    float ex[KCOMP], ssum = 0.f;
    for (int kk = 0; kk < KCOMP; kk++) { ex[kk] = expf(imp[kk] - mx); ssum += ex[kk]; }
    tc = TC0_C + (1.f - expf(-LAM_S * (float)epoch[0])) * (TCMAX_C - TC0_C);
    for (int kk = 0; kk < KCOMP; kk++) {
      float pi = ex[kk] / ssum;
      gates[kk] = fminf(fmaxf((pi - tc) / EPS_G + 0.5f, 0.f), 1.f);
    }
    int am = 0; float bv2 = gates[0];
    for (int kk = 1; kk < KCOMP; kk++) if (gates[kk] > bv2) { bv2 = gates[kk]; am = kk; }
    gates[am] = fmaxf(gates[am], 1.f);
  }
  if (t == 0) {
    scal[12 + k] = gates[k];
    if (k == 0) for (int kk = 0; kk < KCOMP; kk++) out_gates[kk] = gates[kk];
  }
  float imp[4];
#pragma unroll
  for (int j = 0; j < 4; j++) {
    int e = t + j * 1024;
    imp[j] = (e < MAXSE) ? impE[k * 512 + e] : 0.f;
  }
  float m = fmaxf(fmaxf(imp[0], imp[1]), fmaxf(imp[2], imp[3]));
  for (int o = 32; o > 0; o >>= 1) m = fmaxf(m, __shfl_xor(m, o, 64));
  __syncthreads();
  if ((t & 63) == 0) red[t >> 6] = m;
  __syncthreads();
  m = red[0];
#pragma unroll
  for (int i = 1; i < 16; i++) m = fmaxf(m, red[i]);
  float p[4], psum = 0.f;
#pragma unroll
  for (int j = 0; j < 4; j++) { p[j] = expf(imp[j] - m); psum += p[j]; }
  float S = blockReduceSum16(psum, red, t);
  float pi[4], tot = 0.f;
#pragma unroll
  for (int j = 0; j < 4; j++) { pi[j] = p[j] / S; tot += pi[j]; }
  float T = blockReduceSum16(tot, red, t);
  float mean = T / (float)EE;
  float devs = 0.f;
#pragma unroll
  for (int j = 0; j < 4; j++) { float d = pi[j] - mean; devs = fmaf(d, d, devs); }
  float V = blockReduceSum16(devs, red, t);
  float stdv = sqrtf(V / (float)(EE - 1));
  float theta = fminf(tc, mean + stdv);
  float eg[4], egsum = 0.f;
#pragma unroll
  for (int j = 0; j < 4; j++) {
    eg[j] = fminf(fmaxf((pi[j] - theta) / EPS_G + 0.5f, 0.f), 1.f);
    egsum += eg[j];
  }
  float EGS = blockReduceSum16(egsum, red, t);
  float bv = -1e30f; int bi = 0x7fffffff;
#pragma unroll
  for (int j = 0; j < 4; j++) if (pi[j] > bv) { bv = pi[j]; bi = t + j * 1024; }
  for (int o = 32; o > 0; o >>= 1) {
    float ov = __shfl_xor(bv, o, 64); int oi = __shfl_xor(bi, o, 64);
    if (ov > bv || (ov == bv && oi < bi)) { bv = ov; bi = oi; }
  }
  __syncthreads();
  if ((t & 63) == 0) { red[t >> 6] = bv; redi[t >> 6] = bi; }
  __syncthreads();
  float abv = red[0]; int abi = redi[0];
#pragma unroll
  for (int i = 1; i < 16; i++) {
    float ov = red[i]; int oi = redi[i];
    if (ov > abv || (ov == abv && oi < abi)) { abv = ov; abi = oi; }
  }
  float g = gates[k];
#pragma unroll
  for (int j = 0; j < 4; j++) {
    int e = t + j * 1024;
    float egv = eg[j];
    if (EGS < 1.f && e == abi) egv = 1.f;
    out_eg[(size_t)k * EE + e] = egv;
    float eff = (g > 0.5f) ? egv : 1.f;
    egscaled[k * EE + e] = g * eff;
  }
}

// ---------- dispatch 4: Hp row compose + write + adjacency rowscan, block per (n,k) ----------
// g==0 fast path: the whole row is exactly zero (egscaled = 0*eff) -> stream zeros.
__global__ void k_hprow(const unsigned* __restrict__ emask,
                        const int* __restrict__ ncnt, const unsigned short* __restrict__ nelist,
                        const float* __restrict__ egs, const float* __restrict__ scal,
                        const float* __restrict__ xhat, const float* __restrict__ xnorm,
                        float* __restrict__ out, float* __restrict__ z) {
  __shared__ float row[EE];
  __shared__ unsigned short elds[MAXNE];
  __shared__ unsigned wpart[4][64];
  __shared__ unsigned short list[2048];
  __shared__ int cnt_s;
  __shared__ float sred[4];
  int k = blockIdx.y, n = blockIdx.x, t = threadIdx.x;
  float g = scal[12 + k];
  float4* o4 = (float4*)(out + ((size_t)(k * NN + n)) * EE);
  if (g <= 0.f) {
    float4 z4 = {0.f, 0.f, 0.f, 0.f};
#pragma unroll
    for (int i = 0; i < 4; i++) o4[t + i * 256] = z4;
    if (t == 0) z[k * NN + n] = 0.f;
    return;
  }
  int ec = ncnt[k * NN + n]; if (ec > MAXNE) ec = MAXNE;
  if (t < ec) elds[t] = nelist[((size_t)(k * NN + n)) * MAXNE + t];
  float4* row4 = (float4*)row;
  float4 z4 = {0.f, 0.f, 0.f, 0.f};
#pragma unroll
  for (int i = 0; i < 4; i++) row4[t + i * 256] = z4;
  if (t == 0) cnt_s = 0;
  __syncthreads();
  if (t < ec) {
    int e = elds[t];
    row[e] = egs[k * EE + e];
  }
  __syncthreads();
#pragma unroll
  for (int i = 0; i < 4; i++) o4[t + i * 256] = row4[t + i * 256];
  // ---- rowscan ----
  int lane = t & 63, wv = t >> 6;
  unsigned acc = 0;
  for (int it = wv; it < ec; it += 4) {
    int e = (int)elds[it];
    if (row[e] > 0.f) acc |= emask[((size_t)(k * EE) + e) * 64 + lane];
  }
  wpart[wv][lane] = acc;
  __syncthreads();
  if (t < 64) {
    unsigned w = wpart[0][t] | wpart[1][t] | wpart[2][t] | wpart[3][t];
    if (t == (n >> 5)) w &= ~(1u << (n & 31));
    int c = __popc(w);
    if (c > 0) {
      int base = atomicAdd(&cnt_s, c);
      while (w) {
        int b = __builtin_ctz(w); w &= w - 1;
        list[base++] = (unsigned short)((t << 5) + b);
      }
    }
  }
  __syncthreads();
  int cnt = cnt_s;
  if (cnt == 0) { if (t == 0) z[k * NN + n] = 0.f; return; }
  int fc = lane & 31, hh = lane >> 5;
  float4 xn4 = ((const float4*)xhat)[(size_t)n * 32 + fc];
  float a = 0.f;
  for (int it = wv * 2 + hh; it < cnt; it += 8) {
    int m = (int)list[it];
    float4 xm = ((const float4*)xhat)[(size_t)m * 32 + fc];
    a += xn4.x * xm.x + xn4.y * xm.y + xn4.z * xm.z + xn4.w * xm.w;
  }
  for (int o = 32; o > 0; o >>= 1) a += __shfl_xor(a, o, 64);
  if (lane == 0) sred[wv] = a;
  __syncthreads();
  if (t == 0) {
    float s = sred[0] + sred[1] + sred[2] + sred[3];
    z[k * NN + n] = (s / (float)cnt) * xnorm[n];
  }
}

// ---------- dispatch 5: npi = softmax(z) per k ----------
__global__ void k_npi(const float* __restrict__ z, float* __restrict__ out_npi) {
  __shared__ float red[4];
  int k = blockIdx.x, t = threadIdx.x;
  float v[8]; float m = -1e30f;
#pragma unroll
  for (int j = 0; j < 8; j++) { v[j] = z[k * NN + t + j * 256]; m = fmaxf(m, v[j]); }
  for (int o = 32; o > 0; o >>= 1) m = fmaxf(m, __shfl_xor(m, o, 64));
  if ((t & 63) == 0) red[t >> 6] = m;
  __syncthreads();
  m = fmaxf(fmaxf(red[0], red[1]), fmaxf(red[2], red[3]));
  __syncthreads();
  float pe[8]; float s = 0.f;
#pragma unroll
  for (int j = 0; j < 8; j++) { pe[j] = expf(v[j] - m); s += pe[j]; }
  for (int o = 32; o > 0; o >>= 1) s += __shfl_xor(s, o, 64);
  if ((t & 63) == 0) red[t >> 6] = s;
  __syncthreads();
  s = red[0] + red[1] + red[2] + red[3];
#pragma unroll
  for (int j = 0; j < 8; j++) out_npi[k * NN + t + j * 256] = pe[j] / s;
}

extern "C" void kernel_launch(void* const* d_in, const int* in_sizes, int n_in,
                              void* d_out, int out_size, void* d_ws, size_t ws_size,
                              hipStream_t stream) {
  const float* H     = (const float*)d_in[0];
  const float* X     = (const float*)d_in[1];
  const int*   epoch = (const int*)d_in[2];
  const float* w1    = (const float*)d_in[3];
  const float* b1    = (const float*)d_in[4];
  const float* w2    = (const float*)d_in[5];
  const float* b2    = (const float*)d_in[6];
  const float* compW = (const float*)d_in[7];
  const float* aw1   = (const float*)d_in[8];
  const float* ab1   = (const float*)d_in[9];
  const float* aw2   = (const float*)d_in[10];
  const float* ab2   = (const float*)d_in[11];

  char* ws = (char*)d_ws;
  float* xhat  = (float*)(ws + OFF_XHAT);
  float* xnorm = (float*)(ws + OFF_XNORM);
  float* scal  = (float*)(ws + OFF_SCAL);
  int*   ncnt  = (int*)(ws + OFF_NCNT);
  unsigned* emask = (unsigned*)(ws + OFF_EMASK);
  unsigned short* nelist = (unsigned short*)(ws + OFF_NELIST);
  float* impE  = (float*)(ws + OFF_IMPE);
  float* egs   = (float*)(ws + OFF_EGS);
  float* zbuf  = (float*)(ws + OFF_Z);

  float* out       = (float*)d_out;
  float* out_gates = out + (size_t)KCOMP * NN * EE;
  float* out_eg    = out_gates + KCOMP;
  float* out_npi   = out_eg + (size_t)KCOMP * EE;

  k_scanx<<<384, 1024, 0, stream>>>((const float4*)H, emask, X, xhat, xnorm, scal);
  k_mlnel<<<dim3(333, KCOMP), 256, 0, stream>>>(X, w1, b1, w2, b2, aw1, ab1, aw2, ab2,
                                                (const float4*)compW, scal,
                                                emask, ncnt, nelist, xhat, impE);
  k_edgegate<<<KCOMP, 1024, 0, stream>>>(impE, scal, epoch, out_gates, egs, out_eg);
  k_hprow<<<dim3(NN, KCOMP), 256, 0, stream>>>(emask, ncnt, nelist, egs, scal, xhat, xnorm,
                                               out, zbuf);
  k_npi<<<KCOMP, 256, 0, stream>>>(zbuf, out_npi);
}